// Round 6
// baseline (767.413 us; speedup 1.0000x reference)
//
#include <hip/hip_runtime.h>

#define Bc 16
#define Tc 16
#define Cc 512
#define Kc 64
#define Sc 196
#define KS (Kc*Sc)          // 12544
#define BKS (Bc*Kc*Sc)      // 200704
#define TBKS (Tc*BKS)       // 3211264
#define PART_N (8*16*64*512)  // 4194304 floats
#define GFIN (16*64*512)      // 524288 stride between tg partials

#define GPLANE 288                    // 18 rows * 16 cols per plane
#define GP_TOT (16 + 64*GPLANE + 16)  // 18464 floats incl guards

__device__ __forceinline__ float sigmoid_f(float x) { return 1.f / (1.f + __expf(-x)); }
__device__ __forceinline__ float tanh_f(float x) { return 1.f - 2.f / (__expf(2.f * x) + 1.f); }

// ---------------- transpose share_w: wt[c][k] = w[k][c] ----------------
__global__ __launch_bounds__(256) void k_transpose_w(const float* __restrict__ w, float* __restrict__ wt) {
    int idx = blockIdx.x * 256 + threadIdx.x;
    if (idx < Kc * Cc) {
        int k = idx & 63, c = idx >> 6;
        wt[idx] = w[k * Cc + c];
    }
}

// ---------------- conv1x1: one n per block, wave=8k (weights via s_load), lane=4px ----------------
__global__ __launch_bounds__(512) void k_conv1x1(const float* __restrict__ x, const float* __restrict__ wt,
                                                 const float* __restrict__ bias, float* __restrict__ wxb) {
    __shared__ float Xs[32 * Sc];   // 25 KB
    const int n = blockIdx.x;
    const int tid = threadIdx.x;
    const int kw = __builtin_amdgcn_readfirstlane((tid >> 6) << 3);  // wave k-base
    const int lane = tid & 63;
    const int sbase = (lane < 49 ? lane : 48) * 4;
    const bool act = (lane < 49);
    const float* xg = x + (size_t)n * (Cc * Sc);

    float acc[8][4] = {};
    for (int c0 = 0; c0 < Cc; c0 += 32) {
        __syncthreads();
        {   // linear float4 copy: Xs[0..6271] = xg[c0*196 .. +6271]
            const float4* src = (const float4*)(xg + (size_t)c0 * Sc);
            float4* dst = (float4*)Xs;
            for (int q = tid; q < 1568; q += 512) dst[q] = src[q];
        }
        __syncthreads();
#pragma unroll 4
        for (int cc = 0; cc < 32; ++cc) {
            const float* wp = wt + (size_t)(c0 + cc) * Kc + kw;   // uniform -> s_load
            float4 xv = *(const float4*)&Xs[cc * Sc + sbase];
#pragma unroll
            for (int i = 0; i < 8; ++i) {
                float wv = wp[i];
                acc[i][0] += wv * xv.x;
                acc[i][1] += wv * xv.y;
                acc[i][2] += wv * xv.z;
                acc[i][3] += wv * xv.w;
            }
        }
    }
    if (act) {
        const int t = n & 15, b = n >> 4;
        float* op = wxb + (((size_t)t * Bc + b) * Kc + kw) * Sc + sbase;
#pragma unroll
        for (int i = 0; i < 8; ++i) {
            float bv = bias[kw + i];
            *(float4*)(op + (size_t)i * Sc) =
                make_float4(acc[i][0] + bv, acc[i][1] + bv, acc[i][2] + bv, acc[i][3] + bv);
        }
    }
}

// ---------------- GRU t=0: h=0 -> assign0 = (1-sig(wxb))*tanh(wxb) ----------------
__global__ __launch_bounds__(256) void k_gru_t0(const float* __restrict__ wxb, float* __restrict__ assign) {
    int i = blockIdx.x * 256 + threadIdx.x;   // grid 196 * 256 * 4 = BKS exactly
    float4 v = ((const float4*)wxb)[i];
    float4 o;
    o.x = (1.f - sigmoid_f(v.x)) * tanh_f(v.x);
    o.y = (1.f - sigmoid_f(v.y)) * tanh_f(v.y);
    o.z = (1.f - sigmoid_f(v.z)) * tanh_f(v.z);
    o.w = (1.f - sigmoid_f(v.w)) * tanh_f(v.w);
    ((float4*)assign)[i] = o;
}

__device__ __forceinline__ void pad_init(float* lds, int tid, int nthr) {
    // zero only pad cells: rows 0,1,16,17 (all 16 cols) + rows 2..15 cols {0,15}; plus guards
    float* P = lds + 16;
    for (int i = tid; i < 64 * 92; i += nthr) {
        int kk = i / 92, pid = i - kk * 92;
        int row, col;
        if (pid < 64) { int rr = pid >> 4; row = (rr < 2) ? rr : rr + 14; col = pid & 15; }
        else { int q = pid - 64; row = 2 + (q >> 1); col = (q & 1) ? 15 : 0; }
        P[kk * GPLANE + row * 16 + col] = 0.f;
    }
    if (tid < 16) { lds[tid] = 0.f; lds[GP_TOT - 16 + tid] = 0.f; }
}

// ---------------- GRU gates: 1024 thr, 16 waves = (k-pair kp) x (ki-eighth kih) ----------------
__global__ __launch_bounds__(1024) void k_gru_gates(const float* __restrict__ assign,
        const float* __restrict__ wxb, const float* __restrict__ Uz, const float* __restrict__ Ur,
        float* __restrict__ zb, float* __restrict__ rh, int t) {
    extern __shared__ float lds[];
    float* P = lds + 16;
    float* red = lds + GP_TOT;
    const int b = blockIdx.x;
    const int k0 = blockIdx.y * 4;
    const int tid = threadIdx.x;
    const float* wxb_t = wxb + (size_t)t * BKS;

    pad_init(lds, tid, 1024);
    __syncthreads();
    {
        const float* hb = assign + (size_t)(t - 1) * BKS + (size_t)b * KS;
#pragma unroll 4
        for (int i = tid; i < KS; i += 1024) {
            int kk = i / Sc, s = i - kk * Sc;
            int y = s / 14, xx = s - y * 14;
            P[kk * GPLANE + (y + 2) * 16 + xx + 1] = hb[i];
        }
    }
    __syncthreads();

    const int wv = __builtin_amdgcn_readfirstlane(tid >> 6);
    const int lane = tid & 63;
    const int kp = wv >> 3, kih = wv & 7;
    const int yp = lane >> 2, xq = (lane & 3) << 2;
    const float* uz0 = Uz + (size_t)(k0 + kp * 2) * 576 + kih * 72;
    const float* ur0 = Ur + (size_t)(k0 + kp * 2) * 576 + kih * 72;
    float az[2][4] = {}, ar[2][4] = {};
    const float* Pw = P + (size_t)(kih * 8) * GPLANE + yp * 16 + xq;
#pragma unroll 2
    for (int ki = 0; ki < 8; ++ki) {
        const float* pk = Pw + ki * GPLANE;
#pragma unroll
        for (int dy = 0; dy < 3; ++dy) {
            const float* row = pk + dy * 16;
            float4 m = *(const float4*)row;
            float e0 = row[-1], e4 = row[4];
#pragma unroll
            for (int r = 0; r < 2; ++r) {
                const float* wz = uz0 + r * 576 + ki * 9 + dy * 3;
                float c0 = wz[0], c1 = wz[1], c2 = wz[2];
                az[r][0] += c0*e0  + c1*m.x + c2*m.y;
                az[r][1] += c0*m.x + c1*m.y + c2*m.z;
                az[r][2] += c0*m.y + c1*m.z + c2*m.w;
                az[r][3] += c0*m.z + c1*m.w + c2*e4;
                const float* wr = ur0 + r * 576 + ki * 9 + dy * 3;
                float d0 = wr[0], d1 = wr[1], d2 = wr[2];
                ar[r][0] += d0*e0  + d1*m.x + d2*m.y;
                ar[r][1] += d0*m.x + d1*m.y + d2*m.z;
                ar[r][2] += d0*m.y + d1*m.z + d2*m.w;
                ar[r][3] += d0*m.z + d1*m.w + d2*e4;
            }
        }
    }
    {
        float* rp = red + (size_t)wv * (16 * 64) + lane;
#pragma unroll
        for (int r = 0; r < 2; ++r)
#pragma unroll
            for (int j = 0; j < 4; ++j) {
                rp[(size_t)(r * 4 + j) * 64] = az[r][j];
                rp[(size_t)(8 + r * 4 + j) * 64] = ar[r][j];
            }
    }
    __syncthreads();
    {
        const int yq = lane >> 2;
#pragma unroll
        for (int m = 0; m < 2; ++m) {
            const int o = wv * 2 + m;
            const int kp_o = o >> 4, v = o & 15;
            float s0 = 0.f;
#pragma unroll
            for (int w8 = 0; w8 < 8; ++w8)
                s0 += red[(size_t)((kp_o * 8 + w8) * 16 + v) * 64 + lane];
            const int g = v >> 3, r = (v >> 2) & 1, j = v & 3;
            const int k = k0 + kp_o * 2 + r;
            const int xb = ((lane & 3) << 2) + j;
            if (yq >= 1 && yq <= 14 && xb >= 1 && xb <= 14) {
                const int s = (yq - 1) * 14 + (xb - 1);
                const size_t base = ((size_t)b * Kc + k) * Sc + s;
                float pre = wxb_t[base];
                float sv = sigmoid_f(pre + s0);
                if (g == 0) {
                    zb[base] = sv;
                } else {
                    float hv = P[(size_t)k * GPLANE + (yq + 1) * 16 + xb];
                    rh[base] = sv * hv;
                }
            }
        }
    }
}

// ---------------- GRU out: 1024 thr ----------------
__global__ __launch_bounds__(1024) void k_gru_out(const float* __restrict__ rhin,
        const float* __restrict__ wxb, const float* __restrict__ Uh, const float* __restrict__ zb,
        float* __restrict__ assign, int t) {
    extern __shared__ float lds[];
    float* P = lds + 16;
    float* red = lds + GP_TOT;
    const int b = blockIdx.x;
    const int k0 = blockIdx.y * 4;
    const int tid = threadIdx.x;
    const float* wxb_t = wxb + (size_t)t * BKS;

    pad_init(lds, tid, 1024);
    __syncthreads();
    {
        const float* hb = rhin + (size_t)b * KS;
#pragma unroll 4
        for (int i = tid; i < KS; i += 1024) {
            int kk = i / Sc, s = i - kk * Sc;
            int y = s / 14, xx = s - y * 14;
            P[kk * GPLANE + (y + 2) * 16 + xx + 1] = hb[i];
        }
    }
    __syncthreads();

    const int wv = __builtin_amdgcn_readfirstlane(tid >> 6);
    const int lane = tid & 63;
    const int kp = wv >> 3, kih = wv & 7;
    const int yp = lane >> 2, xq = (lane & 3) << 2;
    const float* uh0 = Uh + (size_t)(k0 + kp * 2) * 576 + kih * 72;
    float ah[2][4] = {};
    const float* Pw = P + (size_t)(kih * 8) * GPLANE + yp * 16 + xq;
#pragma unroll 2
    for (int ki = 0; ki < 8; ++ki) {
        const float* pk = Pw + ki * GPLANE;
#pragma unroll
        for (int dy = 0; dy < 3; ++dy) {
            const float* row = pk + dy * 16;
            float4 m = *(const float4*)row;
            float e0 = row[-1], e4 = row[4];
#pragma unroll
            for (int r = 0; r < 2; ++r) {
                const float* wh = uh0 + r * 576 + ki * 9 + dy * 3;
                float c0 = wh[0], c1 = wh[1], c2 = wh[2];
                ah[r][0] += c0*e0  + c1*m.x + c2*m.y;
                ah[r][1] += c0*m.x + c1*m.y + c2*m.z;
                ah[r][2] += c0*m.y + c1*m.z + c2*m.w;
                ah[r][3] += c0*m.z + c1*m.w + c2*e4;
            }
        }
    }
    {
        float* rp = red + (size_t)wv * (8 * 64) + lane;
#pragma unroll
        for (int r = 0; r < 2; ++r)
#pragma unroll
            for (int j = 0; j < 4; ++j)
                rp[(size_t)(r * 4 + j) * 64] = ah[r][j];
    }
    __syncthreads();
    {
        const int yq = lane >> 2;
        const int o = wv;
        const int kp_o = o >> 3, v = o & 7;
        float s0 = 0.f;
#pragma unroll
        for (int w8 = 0; w8 < 8; ++w8)
            s0 += red[(size_t)((kp_o * 8 + w8) * 8 + v) * 64 + lane];
        const int r = v >> 2, j = v & 3;
        const int k = k0 + kp_o * 2 + r;
        const int xb = ((lane & 3) << 2) + j;
        if (yq >= 1 && yq <= 14 && xb >= 1 && xb <= 14) {
            const int s = (yq - 1) * 14 + (xb - 1);
            const size_t base = ((size_t)b * Kc + k) * Sc + s;
            float pre = wxb_t[base];
            float zv = zb[base];
            float hp = assign[(size_t)(t - 1) * BKS + base];
            float hh = tanh_f(pre + s0);
            assign[(size_t)t * BKS + base] = (1.f - zv) * hh + zv * hp;
        }
    }
}

// ---------------- asum_tot[b][k] = sum_{t,s} assign ----------------
__global__ __launch_bounds__(64) void k_asum(const float* __restrict__ assign, float* __restrict__ asum) {
    const int bk = blockIdx.x;
    const int b = bk >> 6, k = bk & 63;
    float s = 0.f;
    for (int i = threadIdx.x; i < Tc * Sc; i += 64) {
        int t = i / Sc, sp = i - t * Sc;
        s += assign[(((size_t)t * Bc + b) * Kc + k) * Sc + sp];
    }
#pragma unroll
    for (int o = 1; o < 64; o <<= 1) s += __shfl_xor(s, o);
    if (threadIdx.x == 0) asum[bk] = s;
}

// ---------------- einsum: square 8x8 wave mapping, broadcast LDS reads ----------------
// grid (2 ch, 8 tg, 16 b), 256 thr = 4 waves; wave w: c-base w*64; lane=(kt3,ct3): k=kt3*8+i, c=ct3*8+j
__global__ __launch_bounds__(256) void k_einsum(const float* __restrict__ x, const float* __restrict__ assign,
                                                float* __restrict__ part) {
    extern __shared__ float lds[];
    float* As = lds;                 // [196][68]
    float* Xs = lds + 196 * 68;      // [28][256]
    const int ch = blockIdx.x, tg = blockIdx.y, b = blockIdx.z;
    const int tid = threadIdx.x;
    const int w = tid >> 6, lane = tid & 63;
    const int kt3 = lane >> 3, ct3 = lane & 7;
    const int kbase = kt3 * 8;
    const int cbase = w * 64 + ct3 * 8;
    float acc[8][8] = {};
    for (int tt = 0; tt < 2; ++tt) {
        const int t = tg * 2 + tt;
        const int n = b * Tc + t;
        __syncthreads();
        {   // stage As[s][k] transposed, float4 loads along s
            const float* ap = assign + ((size_t)t * Bc + b) * KS;
            for (int q = tid; q < 3136; q += 256) {
                int k = q / 49, s4 = q - k * 49;
                float4 v = *(const float4*)(ap + (size_t)k * Sc + s4 * 4);
                float* dst = As + (size_t)(s4 * 4) * 68 + k;
                dst[0] = v.x; dst[68] = v.y; dst[136] = v.z; dst[204] = v.w;
            }
        }
        for (int sc = 0; sc < 7; ++sc) {
            const int sb = sc * 28;
            __syncthreads();
            {   // stage Xs[s][c]: thread = c, 7 float4 along s
                const float* xp = x + ((size_t)n * Cc + ch * 256 + tid) * Sc + sb;
#pragma unroll
                for (int f = 0; f < 7; ++f) {
                    float4 v = *(const float4*)(xp + f * 4);
                    float* dst = Xs + (size_t)(f * 4) * 256 + tid;
                    dst[0] = v.x; dst[256] = v.y; dst[512] = v.z; dst[768] = v.w;
                }
            }
            __syncthreads();
#pragma unroll 2
            for (int s = 0; s < 28; ++s) {
                const float* ap = As + (size_t)(sb + s) * 68 + kbase;
                float4 a0 = *(const float4*)ap;
                float4 a1 = *(const float4*)(ap + 4);
                const float* xp = Xs + (size_t)s * 256 + cbase;
                float4 x0 = *(const float4*)xp;
                float4 x1 = *(const float4*)(xp + 4);
                float av[8] = {a0.x,a0.y,a0.z,a0.w,a1.x,a1.y,a1.z,a1.w};
                float xv[8] = {x0.x,x0.y,x0.z,x0.w,x1.x,x1.y,x1.z,x1.w};
#pragma unroll
                for (int i = 0; i < 8; ++i)
#pragma unroll
                    for (int j = 0; j < 8; ++j)
                        acc[i][j] += av[i] * xv[j];
            }
        }
    }
#pragma unroll
    for (int i = 0; i < 8; ++i) {
        const int k = kbase + i;
        float* op = part + (((size_t)tg * Bc + b) * Kc + k) * Cc + ch * 256 + cbase;
        *(float4*)op = make_float4(acc[i][0], acc[i][1], acc[i][2], acc[i][3]);
        *(float4*)(op + 4) = make_float4(acc[i][4], acc[i][5], acc[i][6], acc[i][7]);
    }
}

// ---------------- finalize: 8 partials ----------------
__global__ __launch_bounds__(256) void k_finalize(const float* __restrict__ part, const float* __restrict__ asum,
        const float* __restrict__ centers, float* __restrict__ out) {
    __shared__ float invk[Kc];
    __shared__ float wss[4];
    __shared__ float ginv_s;
    const int b = blockIdx.x;
    const int wave = threadIdx.x >> 6, lane = threadIdx.x & 63;
    float gss = 0.f;
    for (int k = wave; k < Kc; k += 4) {
        const float a = asum[b * Kc + k];
        const float* pp = part + ((size_t)b * Kc + k) * Cc;
        const float* cp = centers + (size_t)k * Cc;
        float ss = 0.f;
#pragma unroll
        for (int cpass = 0; cpass < 8; ++cpass) {
            int c = cpass * 64 + lane;
            float v = -a * cp[c];
#pragma unroll
            for (int g = 0; g < 8; ++g) v += pp[c + (size_t)g * GFIN];
            ss += v * v;
        }
#pragma unroll
        for (int o = 1; o < 64; o <<= 1) ss += __shfl_xor(ss, o);
        float inv = 1.f / fmaxf(sqrtf(ss), 1e-12f);
        if (lane == 0) invk[k] = inv;
        gss += ss * inv * inv;
    }
    if (lane == 0) wss[wave] = gss;
    __syncthreads();
    if (threadIdx.x == 0) {
        float g = wss[0] + wss[1] + wss[2] + wss[3];
        ginv_s = 1.f / fmaxf(sqrtf(g), 1e-12f);
    }
    __syncthreads();
    const float gi = ginv_s;
    for (int k = wave; k < Kc; k += 4) {
        const float a = asum[b * Kc + k];
        const float* pp = part + ((size_t)b * Kc + k) * Cc;
        const float* cp = centers + (size_t)k * Cc;
        const float scl = invk[k] * gi;
        float* op = out + ((size_t)b * Kc + k) * Cc;
#pragma unroll
        for (int cpass = 0; cpass < 8; ++cpass) {
            int c = cpass * 64 + lane;
            float v = -a * cp[c];
#pragma unroll
            for (int g = 0; g < 8; ++g) v += pp[c + (size_t)g * GFIN];
            op[c] = v * scl;
        }
    }
}

extern "C" void kernel_launch(void* const* d_in, const int* in_sizes, int n_in,
                              void* d_out, int out_size, void* d_ws, size_t ws_size,
                              hipStream_t stream) {
    (void)in_sizes; (void)n_in; (void)out_size; (void)ws_size;
    const float* x       = (const float*)d_in[0];
    const float* centers = (const float*)d_in[1];
    const float* share_w = (const float*)d_in[2];
    const float* share_b = (const float*)d_in[3];
    const float* Uz      = (const float*)d_in[4];
    const float* Ur      = (const float*)d_in[5];
    const float* Uh      = (const float*)d_in[6];
    float* out = (float*)d_out;
    float* ws  = (float*)d_ws;

    float* part   = ws;                        // [8][16][64][512] = 4.19M floats
    float* wxb    = ws;                        // overlays part (dead before einsum)
    float* assign = ws + (size_t)PART_N;       // [T][B][K][S]
    float* zb     = assign + (size_t)TBKS;
    float* rh     = zb + (size_t)BKS;
    float* wt     = rh + (size_t)BKS;          // [C][K]
    float* asum   = wt + (size_t)Kc * Cc;      // [B][K]

    const size_t gates_lds = (size_t)(GP_TOT + 16 * 16 * 64) * 4;  // 139.4 KB
    const size_t outk_lds  = (size_t)(GP_TOT + 16 * 8 * 64) * 4;   // 106.6 KB
    const size_t ein_lds   = (size_t)(196 * 68 + 28 * 256) * 4;    // 82.0 KB

    k_transpose_w<<<dim3((Kc * Cc + 255) / 256), 256, 0, stream>>>(share_w, wt);
    k_conv1x1<<<dim3(256), 512, 0, stream>>>(x, wt, share_b, wxb);
    k_gru_t0<<<dim3(196), 256, 0, stream>>>(wxb, assign);
    for (int t = 1; t < Tc; ++t) {
        k_gru_gates<<<dim3(16, 16), 1024, gates_lds, stream>>>(assign, wxb, Uz, Ur, zb, rh, t);
        k_gru_out<<<dim3(16, 16), 1024, outk_lds, stream>>>(rh, wxb, Uh, zb, assign, t);
    }
    k_asum<<<dim3(Bc * Kc), 64, 0, stream>>>(assign, asum);
    k_einsum<<<dim3(2, 8, 16), 256, ein_lds, stream>>>(x, assign, part);
    k_finalize<<<dim3(Bc), 256, 0, stream>>>(part, asum, centers, out);
}

// Round 7
// 565.810 us; speedup vs baseline: 1.3563x; 1.3563x over previous
//
#include <hip/hip_runtime.h>

#define Bc 16
#define Tc 16
#define Cc 512
#define Kc 64
#define Sc 196
#define KS (Kc*Sc)          // 12544
#define BKS (Bc*Kc*Sc)      // 200704
#define TBKS (Tc*BKS)       // 3211264
#define GFIN (16*64*512)      // 524288 stride between tg partials
#define PART_N (8*GFIN)       // 4194304 floats

#define GPLANE 288                    // 18 rows * 16 cols per plane
#define GP_TOT (16 + 64*GPLANE + 16)  // 18464 floats incl guards

__device__ __forceinline__ float sigmoid_f(float x) { return 1.f / (1.f + __expf(-x)); }
__device__ __forceinline__ float tanh_f(float x) { return 1.f - 2.f / (__expf(2.f * x) + 1.f); }

// ---------------- transpose share_w: wt[c][k] = w[k][c] ----------------
__global__ __launch_bounds__(256) void k_transpose_w(const float* __restrict__ w, float* __restrict__ wt) {
    int idx = blockIdx.x * 256 + threadIdx.x;
    if (idx < Kc * Cc) {
        int k = idx & 63, c = idx >> 6;
        wt[idx] = w[k * Cc + c];
    }
}

// ---------------- conv1x1: grid 784 x 256; X in LDS, W via wave-uniform s_load ----------------
// wave = 16-k chunk, lane = 1 gs column; acc[16]
__global__ __launch_bounds__(256) void k_conv1x1(const float* __restrict__ x, const float* __restrict__ wt,
                                                 const float* __restrict__ bias, float* __restrict__ wxb) {
    __shared__ float Xs[32][64];
    const int tid = threadIdx.x;
    const int gs0 = blockIdx.x * 64;
    const int kw = __builtin_amdgcn_readfirstlane((tid >> 6) << 4);
    const int lane = tid & 63;
    const int gs_c = gs0 + lane;
    const int n_c = gs_c / Sc, s_c = gs_c - n_c * Sc;
    const float* xcol = x + (size_t)n_c * (Cc * Sc) + s_c;
    const int rgrp = (tid >> 6) * 8;

    float acc[16] = {};
    for (int c0 = 0; c0 < Cc; c0 += 32) {
        __syncthreads();
#pragma unroll
        for (int q = 0; q < 8; ++q)
            Xs[rgrp + q][lane] = xcol[(size_t)(c0 + rgrp + q) * Sc];
        __syncthreads();
#pragma unroll 8
        for (int cc = 0; cc < 32; ++cc) {
            const float xv = Xs[cc][lane];
            const float* wp = wt + (size_t)(c0 + cc) * Kc + kw;   // uniform -> s_load
#pragma unroll
            for (int i = 0; i < 16; ++i) acc[i] += wp[i] * xv;
        }
    }
    const int gs = gs0 + lane;
    const int n = gs / Sc, s = gs - (gs / Sc) * Sc;
    const int t = n & 15, b = n >> 4;
    float* op = wxb + (((size_t)t * Bc + b) * Kc + kw) * Sc + s;
#pragma unroll
    for (int i = 0; i < 16; ++i)
        op[(size_t)i * Sc] = acc[i] + bias[kw + i];
}

// ---------------- GRU t=0: h=0 -> assign0 = (1-sig(wxb))*tanh(wxb) ----------------
__global__ __launch_bounds__(256) void k_gru_t0(const float* __restrict__ wxb, float* __restrict__ assign) {
    int i = blockIdx.x * 256 + threadIdx.x;   // grid 196*256 float4s = BKS
    float4 v = ((const float4*)wxb)[i];
    float4 o;
    o.x = (1.f - sigmoid_f(v.x)) * tanh_f(v.x);
    o.y = (1.f - sigmoid_f(v.y)) * tanh_f(v.y);
    o.z = (1.f - sigmoid_f(v.z)) * tanh_f(v.z);
    o.w = (1.f - sigmoid_f(v.w)) * tanh_f(v.w);
    ((float4*)assign)[i] = o;
}

__device__ __forceinline__ void pad_init(float* lds, int tid, int nthr) {
    float* P = lds + 16;
    for (int i = tid; i < 64 * 92; i += nthr) {
        int kk = i / 92, pid = i - kk * 92;
        int row, col;
        if (pid < 64) { int rr = pid >> 4; row = (rr < 2) ? rr : rr + 14; col = pid & 15; }
        else { int q = pid - 64; row = 2 + (q >> 1); col = (q & 1) ? 15 : 0; }
        P[kk * GPLANE + row * 16 + col] = 0.f;
    }
    if (tid < 16) { lds[tid] = 0.f; lds[GP_TOT - 16 + tid] = 0.f; }
}

__device__ __forceinline__ void stage_plane(float* P, const float* __restrict__ src, int tid, int nthr) {
    const float4* s4p = (const float4*)src;
    for (int q = tid; q < 3136; q += nthr) {
        float4 v = s4p[q];
        int i = q * 4;
        int kk = i / Sc, s = i - kk * Sc;
        float* pp = P + kk * GPLANE;
        float vv[4] = {v.x, v.y, v.z, v.w};
#pragma unroll
        for (int u = 0; u < 4; ++u) {
            int su = s + u;
            int y = su / 14, xx = su - y * 14;
            pp[(y + 2) * 16 + xx + 1] = vv[u];
        }
    }
}

// ---------------- GRU gates: 1024 thr, 16 waves = (k-pair kp) x (ki-eighth kih) ----------------
__global__ __launch_bounds__(1024) void k_gru_gates(const float* __restrict__ assign,
        const float* __restrict__ wxb, const float* __restrict__ Uz, const float* __restrict__ Ur,
        float* __restrict__ zb, float* __restrict__ rh, int t) {
    extern __shared__ float lds[];
    float* P = lds + 16;
    float* red = lds + GP_TOT;
    const int b = blockIdx.x;
    const int k0 = blockIdx.y * 4;
    const int tid = threadIdx.x;
    const float* wxb_t = wxb + (size_t)t * BKS;

    const int wv = __builtin_amdgcn_readfirstlane(tid >> 6);
    const int lane = tid & 63;
    const int yq_e = lane >> 2;
    // ---- epilogue index precompute + prefetch ----
    int kE[2], xbE[2], gE[2]; size_t baseE[2]; bool valE[2]; float preE[2];
#pragma unroll
    for (int m = 0; m < 2; ++m) {
        const int o = wv * 2 + m;
        const int kp_o = o >> 4, v = o & 15;
        gE[m] = v >> 3;
        const int r = (v >> 2) & 1, j = v & 3;
        kE[m] = k0 + kp_o * 2 + r;
        xbE[m] = ((lane & 3) << 2) + j;
        valE[m] = (yq_e >= 1 && yq_e <= 14 && xbE[m] >= 1 && xbE[m] <= 14);
        const int s = (yq_e - 1) * 14 + (xbE[m] - 1);
        baseE[m] = ((size_t)b * Kc + kE[m]) * Sc + (valE[m] ? s : 0);
        preE[m] = valE[m] ? wxb_t[baseE[m]] : 0.f;
    }

    pad_init(lds, tid, 1024);
    stage_plane(P, assign + (size_t)(t - 1) * BKS + (size_t)b * KS, tid, 1024);
    __syncthreads();

    const int kp = wv >> 3, kih = wv & 7;
    const int yp = lane >> 2, xq = (lane & 3) << 2;
    const float* uz0 = Uz + (size_t)(k0 + kp * 2) * 576 + kih * 72;
    const float* ur0 = Ur + (size_t)(k0 + kp * 2) * 576 + kih * 72;
    float az[2][4] = {}, ar[2][4] = {};
    const float* Pw = P + (size_t)(kih * 8) * GPLANE + yp * 16 + xq;
#pragma unroll 2
    for (int ki = 0; ki < 8; ++ki) {
        const float* pk = Pw + ki * GPLANE;
#pragma unroll
        for (int dy = 0; dy < 3; ++dy) {
            const float* row = pk + dy * 16;
            float4 m = *(const float4*)row;
            float e0 = row[-1], e4 = row[4];
#pragma unroll
            for (int r = 0; r < 2; ++r) {
                const float* wz = uz0 + r * 576 + ki * 9 + dy * 3;
                float c0 = wz[0], c1 = wz[1], c2 = wz[2];
                az[r][0] += c0*e0  + c1*m.x + c2*m.y;
                az[r][1] += c0*m.x + c1*m.y + c2*m.z;
                az[r][2] += c0*m.y + c1*m.z + c2*m.w;
                az[r][3] += c0*m.z + c1*m.w + c2*e4;
                const float* wr = ur0 + r * 576 + ki * 9 + dy * 3;
                float d0 = wr[0], d1 = wr[1], d2 = wr[2];
                ar[r][0] += d0*e0  + d1*m.x + d2*m.y;
                ar[r][1] += d0*m.x + d1*m.y + d2*m.z;
                ar[r][2] += d0*m.y + d1*m.z + d2*m.w;
                ar[r][3] += d0*m.z + d1*m.w + d2*e4;
            }
        }
    }
    {
        float* rp = red + (size_t)wv * (16 * 64) + lane;
#pragma unroll
        for (int r = 0; r < 2; ++r)
#pragma unroll
            for (int j = 0; j < 4; ++j) {
                rp[(size_t)(r * 4 + j) * 64] = az[r][j];
                rp[(size_t)(8 + r * 4 + j) * 64] = ar[r][j];
            }
    }
    __syncthreads();
    {
#pragma unroll
        for (int m = 0; m < 2; ++m) {
            const int o = wv * 2 + m;
            const int kp_o = o >> 4, v = o & 15;
            float s0 = 0.f;
#pragma unroll
            for (int w8 = 0; w8 < 8; ++w8)
                s0 += red[(size_t)((kp_o * 8 + w8) * 16 + v) * 64 + lane];
            if (valE[m]) {
                float sv = sigmoid_f(preE[m] + s0);
                if (gE[m] == 0) {
                    zb[baseE[m]] = sv;
                } else {
                    float hv = P[(size_t)kE[m] * GPLANE + (yq_e + 1) * 16 + xbE[m]];
                    rh[baseE[m]] = sv * hv;
                }
            }
        }
    }
}

// ---------------- GRU out: 1024 thr ----------------
__global__ __launch_bounds__(1024) void k_gru_out(const float* __restrict__ rhin,
        const float* __restrict__ wxb, const float* __restrict__ Uh, const float* __restrict__ zb,
        float* __restrict__ assign, int t) {
    extern __shared__ float lds[];
    float* P = lds + 16;
    float* red = lds + GP_TOT;
    const int b = blockIdx.x;
    const int k0 = blockIdx.y * 4;
    const int tid = threadIdx.x;
    const float* wxb_t = wxb + (size_t)t * BKS;

    const int wv = __builtin_amdgcn_readfirstlane(tid >> 6);
    const int lane = tid & 63;
    const int yq_e = lane >> 2;
    // ---- epilogue precompute + prefetch ----
    const int kp_oE = wv >> 3, vE = wv & 7;
    const int rE = vE >> 2, jE = vE & 3;
    const int kE = k0 + kp_oE * 2 + rE;
    const int xbE = ((lane & 3) << 2) + jE;
    const bool valE = (yq_e >= 1 && yq_e <= 14 && xbE >= 1 && xbE <= 14);
    const int sE = (yq_e - 1) * 14 + (xbE - 1);
    const size_t baseE = ((size_t)b * Kc + kE) * Sc + (valE ? sE : 0);
    float preE = 0.f, zvE = 0.f, hpE = 0.f;
    if (valE) {
        preE = wxb_t[baseE];
        zvE = zb[baseE];
        hpE = assign[(size_t)(t - 1) * BKS + baseE];
    }

    pad_init(lds, tid, 1024);
    stage_plane(P, rhin + (size_t)b * KS, tid, 1024);
    __syncthreads();

    const int kp = wv >> 3, kih = wv & 7;
    const int yp = lane >> 2, xq = (lane & 3) << 2;
    const float* uh0 = Uh + (size_t)(k0 + kp * 2) * 576 + kih * 72;
    float ah[2][4] = {};
    const float* Pw = P + (size_t)(kih * 8) * GPLANE + yp * 16 + xq;
#pragma unroll 2
    for (int ki = 0; ki < 8; ++ki) {
        const float* pk = Pw + ki * GPLANE;
#pragma unroll
        for (int dy = 0; dy < 3; ++dy) {
            const float* row = pk + dy * 16;
            float4 m = *(const float4*)row;
            float e0 = row[-1], e4 = row[4];
#pragma unroll
            for (int r = 0; r < 2; ++r) {
                const float* wh = uh0 + r * 576 + ki * 9 + dy * 3;
                float c0 = wh[0], c1 = wh[1], c2 = wh[2];
                ah[r][0] += c0*e0  + c1*m.x + c2*m.y;
                ah[r][1] += c0*m.x + c1*m.y + c2*m.z;
                ah[r][2] += c0*m.y + c1*m.z + c2*m.w;
                ah[r][3] += c0*m.z + c1*m.w + c2*e4;
            }
        }
    }
    {
        float* rp = red + (size_t)wv * (8 * 64) + lane;
#pragma unroll
        for (int r = 0; r < 2; ++r)
#pragma unroll
            for (int j = 0; j < 4; ++j)
                rp[(size_t)(r * 4 + j) * 64] = ah[r][j];
    }
    __syncthreads();
    {
        float s0 = 0.f;
#pragma unroll
        for (int w8 = 0; w8 < 8; ++w8)
            s0 += red[(size_t)((kp_oE * 8 + w8) * 8 + vE) * 64 + lane];
        if (valE) {
            float hh = tanh_f(preE + s0);
            assign[(size_t)t * BKS + baseE] = (1.f - zvE) * hh + zvE * hpE;
        }
    }
}

// ---------------- einsum: grid (4 ch,8 tg,16 b) = 512 blocks, 256 thr, 68KB LDS (2 blk/CU) ----------------
__global__ __launch_bounds__(256) void k_einsum(const float* __restrict__ x, const float* __restrict__ assign,
                                                float* __restrict__ part) {
    extern __shared__ float lds[];
    float* As = lds;                 // [196][68]
    float* Xs = lds + 196 * 68;      // [28][132]
    const int ch = blockIdx.x, tg = blockIdx.y, b = blockIdx.z;
    const int tid = threadIdx.x;
    const int w = tid >> 6, lane = tid & 63;
    const int kt3 = lane >> 3, ct3 = lane & 7;
    const int kbase = kt3 * 8;
    const int cbase = w * 32 + ct3 * 4;       // c within 128
    float4 acc[8] = {};
    for (int tt = 0; tt < 2; ++tt) {
        const int t = tg * 2 + tt;
        const int n = b * Tc + t;
        __syncthreads();
        {   // As[s][k]: per unit (kq quad, s): 4 strided scalar reads -> one b128 write
            const float* ap = assign + ((size_t)t * Bc + b) * KS;
            for (int q = tid; q < 3136; q += 256) {
                int kq = q / Sc, s = q - kq * Sc;
                int k4 = kq * 4;
                float4 v;
                v.x = ap[(size_t)(k4 + 0) * Sc + s];
                v.y = ap[(size_t)(k4 + 1) * Sc + s];
                v.z = ap[(size_t)(k4 + 2) * Sc + s];
                v.w = ap[(size_t)(k4 + 3) * Sc + s];
                *(float4*)(As + (size_t)s * 68 + k4) = v;
            }
        }
        for (int sc = 0; sc < 7; ++sc) {
            const int sb = sc * 28;
            __syncthreads();
            {   // Xs[s][c] for 128 c, 28 s; thread = (c, s-half 16/12)
                const int c = tid & 127, sh = tid >> 7;
                const float* xp = x + ((size_t)n * Cc + ch * 128 + c) * Sc + sb + sh * 16;
                const int nf = sh ? 3 : 4;
                for (int f = 0; f < nf; ++f) {
                    float4 v = *(const float4*)(xp + f * 4);
                    float* dst = Xs + (size_t)(sh * 16 + f * 4) * 132 + c;
                    dst[0] = v.x; dst[132] = v.y; dst[264] = v.z; dst[396] = v.w;
                }
            }
            __syncthreads();
#pragma unroll 4
            for (int s = 0; s < 28; ++s) {
                const float* ap = As + (size_t)(sb + s) * 68 + kbase;
                float4 a0 = *(const float4*)ap;
                float4 a1 = *(const float4*)(ap + 4);
                float4 xv = *(const float4*)(Xs + (size_t)s * 132 + cbase);
                float av[8] = {a0.x,a0.y,a0.z,a0.w,a1.x,a1.y,a1.z,a1.w};
#pragma unroll
                for (int i = 0; i < 8; ++i) {
                    acc[i].x += av[i] * xv.x;
                    acc[i].y += av[i] * xv.y;
                    acc[i].z += av[i] * xv.z;
                    acc[i].w += av[i] * xv.w;
                }
            }
        }
    }
#pragma unroll
    for (int i = 0; i < 8; ++i) {
        const int k = kbase + i;
        float* op = part + (((size_t)tg * Bc + b) * Kc + k) * Cc + ch * 128 + cbase;
        *(float4*)op = acc[i];
    }
}

// ---------------- reduce: per (b,k) block -- asum + partial-sum + center-subtract + sumsq ----------------
__global__ __launch_bounds__(256) void k_reduce(const float* __restrict__ assign, const float* __restrict__ part,
        const float* __restrict__ centers, float* __restrict__ vlad, float* __restrict__ norm2) {
    __shared__ float redw[4];
    __shared__ float a_s;
    const int blk = blockIdx.x;
    const int b = blk >> 6, k = blk & 63;
    const int tid = threadIdx.x;
    const int wave = tid >> 6, lane = tid & 63;
    const size_t bkoff = ((size_t)b * Kc + k) * Sc;
    float s = 0.f;
    for (int q = tid; q < 784; q += 256) {
        int t = q / 49, s4 = q - t * 49;
        float4 v = *(const float4*)(assign + (size_t)t * BKS + bkoff + s4 * 4);
        s += (v.x + v.y) + (v.z + v.w);
    }
#pragma unroll
    for (int o = 1; o < 64; o <<= 1) s += __shfl_xor(s, o);
    if (lane == 0) redw[wave] = s;
    __syncthreads();
    if (tid == 0) a_s = redw[0] + redw[1] + redw[2] + redw[3];
    __syncthreads();
    const float a = a_s;
    const size_t base = ((size_t)b * Kc + k) * Cc;
    const int c = tid * 2;
    float2 acc2 = make_float2(0.f, 0.f);
#pragma unroll
    for (int g = 0; g < 8; ++g) {
        float2 p = *(const float2*)(part + (size_t)g * GFIN + base + c);
        acc2.x += p.x; acc2.y += p.y;
    }
    float2 cv = *(const float2*)(centers + (size_t)k * Cc + c);
    float v0 = acc2.x - a * cv.x, v1 = acc2.y - a * cv.y;
    *(float2*)(vlad + base + c) = make_float2(v0, v1);
    float ss = v0 * v0 + v1 * v1;
#pragma unroll
    for (int o = 1; o < 64; o <<= 1) ss += __shfl_xor(ss, o);
    __syncthreads();
    if (lane == 0) redw[wave] = ss;
    __syncthreads();
    if (tid == 0) norm2[blk] = redw[0] + redw[1] + redw[2] + redw[3];
}

// ---------------- norms: per b, 64 lanes = 64 k ----------------
__global__ __launch_bounds__(64) void k_norms(const float* __restrict__ norm2, float* __restrict__ scl) {
    const int b = blockIdx.x;
    const int k = threadIdx.x;
    float ss = norm2[b * Kc + k];
    float inv = 1.f / fmaxf(sqrtf(ss), 1e-12f);
    float g = ss * inv * inv;
#pragma unroll
    for (int o = 1; o < 64; o <<= 1) g += __shfl_xor(g, o);
    float gi = 1.f / fmaxf(sqrtf(g), 1e-12f);
    scl[b * Kc + k] = inv * gi;
}

// ---------------- scale & write out ----------------
__global__ __launch_bounds__(256) void k_scale(const float* __restrict__ vlad, const float* __restrict__ scl,
                                               float* __restrict__ out) {
    const int blk = blockIdx.x;           // b*16 + kt
    const int b = blk >> 4, kt = blk & 15;
    const int tid = threadIdx.x;
    const int kk = tid >> 6, lane = tid & 63;
    const int k = kt * 4 + kk;
    const float sv = scl[b * Kc + k];
    const float* vp = vlad + ((size_t)b * Kc + k) * Cc + lane * 8;
    float* op = out + ((size_t)b * Kc + k) * Cc + lane * 8;
    float4 v0 = *(const float4*)vp;
    float4 v1 = *(const float4*)(vp + 4);
    *(float4*)op = make_float4(v0.x * sv, v0.y * sv, v0.z * sv, v0.w * sv);
    *(float4*)(op + 4) = make_float4(v1.x * sv, v1.y * sv, v1.z * sv, v1.w * sv);
}

extern "C" void kernel_launch(void* const* d_in, const int* in_sizes, int n_in,
                              void* d_out, int out_size, void* d_ws, size_t ws_size,
                              hipStream_t stream) {
    (void)in_sizes; (void)n_in; (void)out_size; (void)ws_size;
    const float* x       = (const float*)d_in[0];
    const float* centers = (const float*)d_in[1];
    const float* share_w = (const float*)d_in[2];
    const float* share_b = (const float*)d_in[3];
    const float* Uz      = (const float*)d_in[4];
    const float* Ur      = (const float*)d_in[5];
    const float* Uh      = (const float*)d_in[6];
    float* out = (float*)d_out;
    float* ws  = (float*)d_ws;

    float* part   = ws;                        // [8][16][64][512]
    float* wxb    = ws;                        // overlays part (dead before einsum)
    float* vlad   = ws;                        // = part0 region, written by k_reduce
    float* assign = ws + (size_t)PART_N;       // [T][B][K][S]
    float* zb     = assign + (size_t)TBKS;
    float* rh     = zb + (size_t)BKS;
    float* wt     = rh + (size_t)BKS;          // [C][K]
    float* norm2  = wt + (size_t)Kc * Cc;      // [B*K]
    float* scl    = norm2 + (size_t)Bc * Kc;   // [B*K]

    const size_t gates_lds = (size_t)(GP_TOT + 16 * 16 * 64) * 4;  // 139.4 KB
    const size_t outk_lds  = (size_t)(GP_TOT + 16 * 8 * 64) * 4;   // 106.6 KB
    const size_t ein_lds   = (size_t)(196 * 68 + 28 * 132) * 4;    // 68.1 KB

    k_transpose_w<<<dim3((Kc * Cc + 255) / 256), 256, 0, stream>>>(share_w, wt);
    k_conv1x1<<<dim3(784), 256, 0, stream>>>(x, wt, share_b, wxb);
    k_gru_t0<<<dim3(196), 256, 0, stream>>>(wxb, assign);
    for (int t = 1; t < Tc; ++t) {
        k_gru_gates<<<dim3(16, 16), 1024, gates_lds, stream>>>(assign, wxb, Uz, Ur, zb, rh, t);
        k_gru_out<<<dim3(16, 16), 1024, outk_lds, stream>>>(rh, wxb, Uh, zb, assign, t);
    }
    k_einsum<<<dim3(4, 8, 16), 256, ein_lds, stream>>>(x, assign, part);
    k_reduce<<<dim3(Bc * Kc), 256, 0, stream>>>(assign, part, centers, vlad, norm2);
    k_norms<<<dim3(Bc), 64, 0, stream>>>(norm2, scl);
    k_scale<<<dim3(256), 256, 0, stream>>>(vlad, scl, out);
}

// Round 8
// 530.054 us; speedup vs baseline: 1.4478x; 1.0675x over previous
//
#include <hip/hip_runtime.h>

#define Bc 16
#define Tc 16
#define Cc 512
#define Kc 64
#define Sc 196
#define KS (Kc*Sc)          // 12544
#define BKS (Bc*Kc*Sc)      // 200704
#define TBKS (Tc*BKS)       // 3211264
#define GFIN (16*64*512)    // 524288
#define PART_N (8*GFIN)     // 4194304
#define PL 288              // 18 rows * 16 cols per plane
#define PLB (Kc*PL)         // 18432 floats per b

__device__ __forceinline__ float sigmoid_f(float x) { return 1.f / (1.f + __expf(-x)); }
__device__ __forceinline__ float tanh_f(float x) { return 1.f - 2.f / (__expf(2.f * x) + 1.f); }

// ---------------- transpose share_w: wt[c][k] = w[k][c] ----------------
__global__ __launch_bounds__(256) void k_transpose_w(const float* __restrict__ w, float* __restrict__ wt) {
    int idx = blockIdx.x * 256 + threadIdx.x;
    if (idx < Kc * Cc) {
        int k = idx & 63, c = idx >> 6;
        wt[idx] = w[k * Cc + c];
    }
}

// ---------------- conv1x1: 64-row chunks, reg-double-buffered X staging, W via s_load ----------------
__global__ __launch_bounds__(256) void k_conv1x1(const float* __restrict__ x, const float* __restrict__ wt,
                                                 const float* __restrict__ bias, float* __restrict__ wxb) {
    __shared__ float Xs[64][64];
    const int tid = threadIdx.x;
    const int gs0 = blockIdx.x * 64;
    const int kw = __builtin_amdgcn_readfirstlane((tid >> 6) << 4);
    const int lane = tid & 63;
    const int rbase = (tid >> 6) * 16;
    const int gs_c = gs0 + lane;
    const int n_c = gs_c / Sc, s_c = gs_c - n_c * Sc;
    const float* xcol = x + (size_t)n_c * (Cc * Sc) + s_c;

    float xr[16];
#pragma unroll
    for (int q = 0; q < 16; ++q) xr[q] = xcol[(size_t)(rbase + q) * Sc];
    float acc[16] = {};
    for (int c0 = 0; c0 < Cc; c0 += 64) {
        __syncthreads();
#pragma unroll
        for (int q = 0; q < 16; ++q) Xs[rbase + q][lane] = xr[q];
        __syncthreads();
        if (c0 + 64 < Cc) {
#pragma unroll
            for (int q = 0; q < 16; ++q) xr[q] = xcol[(size_t)(c0 + 64 + rbase + q) * Sc];
        }
#pragma unroll 8
        for (int cc = 0; cc < 64; ++cc) {
            const float xv = Xs[cc][lane];
            const float* wp = wt + (size_t)(c0 + cc) * Kc + kw;   // wave-uniform -> s_load
#pragma unroll
            for (int i = 0; i < 16; ++i) acc[i] += wp[i] * xv;
        }
    }
    const int t = n_c & 15, bb = n_c >> 4;
    float* op = wxb + (((size_t)t * Bc + bb) * Kc + kw) * Sc + s_c;
#pragma unroll
    for (int i = 0; i < 16; ++i)
        op[(size_t)i * Sc] = acc[i] + bias[kw + i];
}

// ---------------- GRU t=0: h0=0 -> h = (1-sig(wxb))*tanh(wxb); init planes (pads=0) ----------------
__global__ __launch_bounds__(64) void k_gru_t0(const float* __restrict__ wxb,
        float* __restrict__ hplane, float* __restrict__ rhplane, float* __restrict__ assign) {
    const int blk = blockIdx.x;             // b*64 + k
    const size_t pbase = (size_t)blk * PL;
    const size_t cbase = (size_t)blk * Sc;
    for (int i = threadIdx.x; i < PL; i += 64) {
        int y = i >> 4, xx = i & 15;
        float v = 0.f;
        if (y >= 2 && y <= 15 && xx >= 1 && xx <= 14) {
            int s = (y - 2) * 14 + (xx - 1);
            float pre = wxb[cbase + s];
            v = (1.f - sigmoid_f(pre)) * tanh_f(pre);
            assign[cbase + s] = v;
        }
        hplane[pbase + i] = v;
        rhplane[pbase + i] = 0.f;
    }
}

// ---------------- GRU gates: 512 thr = 8 waves x 8 ki; wave computes all 4k x 2 gates ----------------
// LDS: plane [64][288] (72KB) + red [8][8][256] (64KB)
__global__ __launch_bounds__(512) void k_gru_gates(const float* __restrict__ hplane,
        const float* __restrict__ wxb_t, const float* __restrict__ Uz, const float* __restrict__ Ur,
        float* __restrict__ zb, float* __restrict__ rhplane) {
    extern __shared__ float lds[];
    float* P = lds;
    float* red = lds + PLB;
    const int b = blockIdx.x;
    const int k0 = blockIdx.y * 4;
    const int tid = threadIdx.x;
    const int wv = __builtin_amdgcn_readfirstlane(tid >> 6);
    const int lane = tid & 63;

    // epilogue prefetch (4 outputs per thread)
    float preE[4]; bool validE[4]; size_t baseE[4]; int pxE[4], setE[4];
#pragma unroll
    for (int q = 0; q < 4; ++q) {
        const int o = tid + q * 512;
        setE[q] = o >> 8; pxE[q] = o & 255;
        const int yq = pxE[q] >> 4, xb = pxE[q] & 15;
        validE[q] = (yq >= 1 && yq <= 14 && xb >= 1 && xb <= 14);
        const int kk = setE[q] >> 1;
        const int s = (yq - 1) * 14 + (xb - 1);
        baseE[q] = ((size_t)b * Kc + k0 + kk) * Sc + (validE[q] ? s : 0);
        preE[q] = validE[q] ? wxb_t[baseE[q]] : 0.f;
    }
    {   // linear plane staging
        const float4* src = (const float4*)(hplane + (size_t)b * PLB);
        float4* dst = (float4*)P;
        for (int q = tid; q < PLB / 4; q += 512) dst[q] = src[q];
    }
    __syncthreads();

    const int yp = lane >> 2, xq = (lane & 3) << 2;
    const float* uzb = Uz + (size_t)k0 * 576 + wv * 72;
    const float* urb = Ur + (size_t)k0 * 576 + wv * 72;
    float acc[4][2][4] = {};
    const float* Pw = P + (size_t)(wv * 8) * PL + yp * 16 + xq;
#pragma unroll 2
    for (int ki8 = 0; ki8 < 8; ++ki8) {
        const float* pk = Pw + ki8 * PL;
#pragma unroll
        for (int dy = 0; dy < 3; ++dy) {
            const float* row = pk + dy * 16;
            float4 m = *(const float4*)row;
            float e0 = row[-1], e4 = row[4];
#pragma unroll
            for (int kk = 0; kk < 4; ++kk) {
                const float* wz = uzb + kk * 576 + ki8 * 9 + dy * 3;
                float c0 = wz[0], c1 = wz[1], c2 = wz[2];
                acc[kk][0][0] += c0*e0  + c1*m.x + c2*m.y;
                acc[kk][0][1] += c0*m.x + c1*m.y + c2*m.z;
                acc[kk][0][2] += c0*m.y + c1*m.z + c2*m.w;
                acc[kk][0][3] += c0*m.z + c1*m.w + c2*e4;
                const float* wr = urb + kk * 576 + ki8 * 9 + dy * 3;
                float d0 = wr[0], d1 = wr[1], d2 = wr[2];
                acc[kk][1][0] += d0*e0  + d1*m.x + d2*m.y;
                acc[kk][1][1] += d0*m.x + d1*m.y + d2*m.z;
                acc[kk][1][2] += d0*m.y + d1*m.z + d2*m.w;
                acc[kk][1][3] += d0*m.z + d1*m.w + d2*e4;
            }
        }
    }
    {   // dump: red[wv][set][px], px = lane*4+j  -> b128, conflict-free
        float* rp = red + (size_t)wv * 2048 + lane * 4;
#pragma unroll
        for (int kk = 0; kk < 4; ++kk)
#pragma unroll
            for (int g = 0; g < 2; ++g)
                *(float4*)(rp + (kk * 2 + g) * 256) =
                    make_float4(acc[kk][g][0], acc[kk][g][1], acc[kk][g][2], acc[kk][g][3]);
    }
    __syncthreads();
#pragma unroll
    for (int q = 0; q < 4; ++q) {
        const float* rp = red + setE[q] * 256 + pxE[q];
        float s0 = 0.f;
#pragma unroll
        for (int w8 = 0; w8 < 8; ++w8) s0 += rp[(size_t)w8 * 2048];
        if (validE[q]) {
            float sv = sigmoid_f(preE[q] + s0);
            const int kk = setE[q] >> 1;
            const int k = k0 + kk;
            if ((setE[q] & 1) == 0) {
                zb[baseE[q]] = sv;
            } else {
                const int yq = pxE[q] >> 4, xb = pxE[q] & 15;
                float hv = P[(size_t)k * PL + (yq + 1) * 16 + xb];
                rhplane[(size_t)b * PLB + (size_t)k * PL + (yq + 1) * 16 + xb] = sv * hv;
            }
        }
    }
}

// ---------------- GRU out: 512 thr = 8 waves x 8 ki; wave computes all 4 k ----------------
// LDS: plane 72KB + red [8][4][256] (32KB)
__global__ __launch_bounds__(512) void k_gru_out(const float* __restrict__ rhplane,
        const float* __restrict__ wxb_t, const float* __restrict__ Uh, const float* __restrict__ zb,
        float* __restrict__ hplane, float* __restrict__ assign_t) {
    extern __shared__ float lds[];
    float* P = lds;
    float* red = lds + PLB;
    const int b = blockIdx.x;
    const int k0 = blockIdx.y * 4;
    const int tid = threadIdx.x;
    const int wv = __builtin_amdgcn_readfirstlane(tid >> 6);
    const int lane = tid & 63;

    // epilogue prefetch (2 outputs per thread)
    float preE[2], zvE[2], hpE[2]; bool validE[2]; size_t baseE[2], pposE[2]; int pxE[2], setE[2];
#pragma unroll
    for (int q = 0; q < 2; ++q) {
        const int o = tid + q * 512;
        setE[q] = o >> 8; pxE[q] = o & 255;
        const int yq = pxE[q] >> 4, xb = pxE[q] & 15;
        validE[q] = (yq >= 1 && yq <= 14 && xb >= 1 && xb <= 14);
        const int s = (yq - 1) * 14 + (xb - 1);
        const int k = k0 + setE[q];
        baseE[q] = ((size_t)b * Kc + k) * Sc + (validE[q] ? s : 0);
        pposE[q] = (size_t)b * PLB + (size_t)k * PL + (yq + 1) * 16 + xb;
        preE[q] = 0.f; zvE[q] = 0.f; hpE[q] = 0.f;
        if (validE[q]) {
            preE[q] = wxb_t[baseE[q]];
            zvE[q] = zb[baseE[q]];
            hpE[q] = hplane[pposE[q]];
        }
    }
    {
        const float4* src = (const float4*)(rhplane + (size_t)b * PLB);
        float4* dst = (float4*)P;
        for (int q = tid; q < PLB / 4; q += 512) dst[q] = src[q];
    }
    __syncthreads();

    const int yp = lane >> 2, xq = (lane & 3) << 2;
    const float* uhb = Uh + (size_t)k0 * 576 + wv * 72;
    float acc[4][4] = {};
    const float* Pw = P + (size_t)(wv * 8) * PL + yp * 16 + xq;
#pragma unroll 2
    for (int ki8 = 0; ki8 < 8; ++ki8) {
        const float* pk = Pw + ki8 * PL;
#pragma unroll
        for (int dy = 0; dy < 3; ++dy) {
            const float* row = pk + dy * 16;
            float4 m = *(const float4*)row;
            float e0 = row[-1], e4 = row[4];
#pragma unroll
            for (int kk = 0; kk < 4; ++kk) {
                const float* wh = uhb + kk * 576 + ki8 * 9 + dy * 3;
                float c0 = wh[0], c1 = wh[1], c2 = wh[2];
                acc[kk][0] += c0*e0  + c1*m.x + c2*m.y;
                acc[kk][1] += c0*m.x + c1*m.y + c2*m.z;
                acc[kk][2] += c0*m.y + c1*m.z + c2*m.w;
                acc[kk][3] += c0*m.z + c1*m.w + c2*e4;
            }
        }
    }
    {
        float* rp = red + (size_t)wv * 1024 + lane * 4;
#pragma unroll
        for (int kk = 0; kk < 4; ++kk)
            *(float4*)(rp + kk * 256) = make_float4(acc[kk][0], acc[kk][1], acc[kk][2], acc[kk][3]);
    }
    __syncthreads();
#pragma unroll
    for (int q = 0; q < 2; ++q) {
        const float* rp = red + setE[q] * 256 + pxE[q];
        float s0 = 0.f;
#pragma unroll
        for (int w8 = 0; w8 < 8; ++w8) s0 += rp[(size_t)w8 * 1024];
        if (validE[q]) {
            float hh = tanh_f(preE[q] + s0);
            float hn = (1.f - zvE[q]) * hh + zvE[q] * hpE[q];
            hplane[pposE[q]] = hn;
            assign_t[baseE[q]] = hn;
        }
    }
}

// ---------------- einsum: grid (4 ch,8 tg,16 b), 256 thr, 68KB LDS ----------------
__global__ __launch_bounds__(256) void k_einsum(const float* __restrict__ x, const float* __restrict__ assign,
                                                float* __restrict__ part) {
    extern __shared__ float lds[];
    float* As = lds;                 // [196][68]
    float* Xs = lds + 196 * 68;      // [28][132]
    const int ch = blockIdx.x, tg = blockIdx.y, b = blockIdx.z;
    const int tid = threadIdx.x;
    const int w = tid >> 6, lane = tid & 63;
    const int kt3 = lane >> 3, ct3 = lane & 7;
    const int kbase = kt3 * 8;
    const int cbase = w * 32 + ct3 * 4;
    float4 acc[8] = {};
    for (int tt = 0; tt < 2; ++tt) {
        const int t = tg * 2 + tt;
        const int n = b * Tc + t;
        __syncthreads();
        {
            const float* ap = assign + ((size_t)t * Bc + b) * KS;
            for (int q = tid; q < 3136; q += 256) {
                int kq = q / Sc, s = q - kq * Sc;
                int k4 = kq * 4;
                float4 v;
                v.x = ap[(size_t)(k4 + 0) * Sc + s];
                v.y = ap[(size_t)(k4 + 1) * Sc + s];
                v.z = ap[(size_t)(k4 + 2) * Sc + s];
                v.w = ap[(size_t)(k4 + 3) * Sc + s];
                *(float4*)(As + (size_t)s * 68 + k4) = v;
            }
        }
        for (int sc = 0; sc < 7; ++sc) {
            const int sb = sc * 28;
            __syncthreads();
            {
                const int c = tid & 127, sh = tid >> 7;
                const float* xp = x + ((size_t)n * Cc + ch * 128 + c) * Sc + sb + sh * 16;
                const int nf = sh ? 3 : 4;
                for (int f = 0; f < nf; ++f) {
                    float4 v = *(const float4*)(xp + f * 4);
                    float* dst = Xs + (size_t)(sh * 16 + f * 4) * 132 + c;
                    dst[0] = v.x; dst[132] = v.y; dst[264] = v.z; dst[396] = v.w;
                }
            }
            __syncthreads();
#pragma unroll 4
            for (int s = 0; s < 28; ++s) {
                const float* ap = As + (size_t)(sb + s) * 68 + kbase;
                float4 a0 = *(const float4*)ap;
                float4 a1 = *(const float4*)(ap + 4);
                float4 xv = *(const float4*)(Xs + (size_t)s * 132 + cbase);
                float av[8] = {a0.x,a0.y,a0.z,a0.w,a1.x,a1.y,a1.z,a1.w};
#pragma unroll
                for (int i = 0; i < 8; ++i) {
                    acc[i].x += av[i] * xv.x;
                    acc[i].y += av[i] * xv.y;
                    acc[i].z += av[i] * xv.z;
                    acc[i].w += av[i] * xv.w;
                }
            }
        }
    }
#pragma unroll
    for (int i = 0; i < 8; ++i) {
        const int k = kbase + i;
        float* op = part + (((size_t)tg * Bc + b) * Kc + k) * Cc + ch * 128 + cbase;
        *(float4*)op = acc[i];
    }
}

// ---------------- reduce: per (b,k): asum + partial-sum + center-subtract + sumsq ----------------
__global__ __launch_bounds__(256) void k_reduce(const float* __restrict__ assign, const float* __restrict__ part,
        const float* __restrict__ centers, float* __restrict__ vlad, float* __restrict__ norm2) {
    __shared__ float redw[4];
    __shared__ float a_s;
    const int blk = blockIdx.x;
    const int b = blk >> 6, k = blk & 63;
    const int tid = threadIdx.x;
    const int wave = tid >> 6, lane = tid & 63;
    const size_t bkoff = ((size_t)b * Kc + k) * Sc;
    float s = 0.f;
    for (int q = tid; q < 784; q += 256) {
        int t = q / 49, s4 = q - t * 49;
        float4 v = *(const float4*)(assign + (size_t)t * BKS + bkoff + s4 * 4);
        s += (v.x + v.y) + (v.z + v.w);
    }
#pragma unroll
    for (int o = 1; o < 64; o <<= 1) s += __shfl_xor(s, o);
    if (lane == 0) redw[wave] = s;
    __syncthreads();
    if (tid == 0) a_s = redw[0] + redw[1] + redw[2] + redw[3];
    __syncthreads();
    const float a = a_s;
    const size_t base = ((size_t)b * Kc + k) * Cc;
    const int c = tid * 2;
    float2 acc2 = make_float2(0.f, 0.f);
#pragma unroll
    for (int g = 0; g < 8; ++g) {
        float2 p = *(const float2*)(part + (size_t)g * GFIN + base + c);
        acc2.x += p.x; acc2.y += p.y;
    }
    float2 cv = *(const float2*)(centers + (size_t)k * Cc + c);
    float v0 = acc2.x - a * cv.x, v1 = acc2.y - a * cv.y;
    *(float2*)(vlad + base + c) = make_float2(v0, v1);
    float ss = v0 * v0 + v1 * v1;
#pragma unroll
    for (int o = 1; o < 64; o <<= 1) ss += __shfl_xor(ss, o);
    __syncthreads();
    if (lane == 0) redw[wave] = ss;
    __syncthreads();
    if (tid == 0) norm2[blk] = redw[0] + redw[1] + redw[2] + redw[3];
}

// ---------------- norms ----------------
__global__ __launch_bounds__(64) void k_norms(const float* __restrict__ norm2, float* __restrict__ scl) {
    const int b = blockIdx.x;
    const int k = threadIdx.x;
    float ss = norm2[b * Kc + k];
    float inv = 1.f / fmaxf(sqrtf(ss), 1e-12f);
    float g = ss * inv * inv;
#pragma unroll
    for (int o = 1; o < 64; o <<= 1) g += __shfl_xor(g, o);
    float gi = 1.f / fmaxf(sqrtf(g), 1e-12f);
    scl[b * Kc + k] = inv * gi;
}

// ---------------- scale ----------------
__global__ __launch_bounds__(256) void k_scale(const float* __restrict__ vlad, const float* __restrict__ scl,
                                               float* __restrict__ out) {
    const int blk = blockIdx.x;           // b*16 + kt
    const int b = blk >> 4, kt = blk & 15;
    const int tid = threadIdx.x;
    const int kk = tid >> 6, lane = tid & 63;
    const int k = kt * 4 + kk;
    const float sv = scl[b * Kc + k];
    const float* vp = vlad + ((size_t)b * Kc + k) * Cc + lane * 8;
    float* op = out + ((size_t)b * Kc + k) * Cc + lane * 8;
    float4 v0 = *(const float4*)vp;
    float4 v1 = *(const float4*)(vp + 4);
    *(float4*)op = make_float4(v0.x * sv, v0.y * sv, v0.z * sv, v0.w * sv);
    *(float4*)(op + 4) = make_float4(v1.x * sv, v1.y * sv, v1.z * sv, v1.w * sv);
}

extern "C" void kernel_launch(void* const* d_in, const int* in_sizes, int n_in,
                              void* d_out, int out_size, void* d_ws, size_t ws_size,
                              hipStream_t stream) {
    (void)in_sizes; (void)n_in; (void)out_size; (void)ws_size;
    const float* x       = (const float*)d_in[0];
    const float* centers = (const float*)d_in[1];
    const float* share_w = (const float*)d_in[2];
    const float* share_b = (const float*)d_in[3];
    const float* Uz      = (const float*)d_in[4];
    const float* Ur      = (const float*)d_in[5];
    const float* Uh      = (const float*)d_in[6];
    float* out = (float*)d_out;
    float* ws  = (float*)d_ws;

    // region A (PART_N floats): wxb [T][B][K][S] + rhplane; later overlaid by part/vlad
    float* part    = ws;
    float* vlad    = ws;
    float* wxb     = ws;
    float* rhplane = ws + (size_t)TBKS;              // 294912 floats (fits: PART_N-TBKS = 983040)
    float* assign  = ws + (size_t)PART_N;            // [T][B][K][S]
    float* zb      = assign + (size_t)TBKS;          // [B][K][S]
    float* hplane  = zb + (size_t)BKS;               // [B][64][288]
    float* wt      = hplane + (size_t)Bc * PLB;      // [C][K]
    float* norm2   = wt + (size_t)Kc * Cc;
    float* scl     = norm2 + (size_t)Bc * Kc;

    const size_t gates_lds = (size_t)(PLB + 8 * 8 * 256) * 4;   // 136 KB
    const size_t outk_lds  = (size_t)(PLB + 8 * 4 * 256) * 4;   // 104 KB
    const size_t ein_lds   = (size_t)(196 * 68 + 28 * 132) * 4; // 68.1 KB

    k_transpose_w<<<dim3(128), 256, 0, stream>>>(share_w, wt);
    k_conv1x1<<<dim3(784), 256, 0, stream>>>(x, wt, share_b, wxb);
    k_gru_t0<<<dim3(1024), 64, 0, stream>>>(wxb, hplane, rhplane, assign);
    for (int t = 1; t < Tc; ++t) {
        k_gru_gates<<<dim3(16, 16), 512, gates_lds, stream>>>(hplane, wxb + (size_t)t * BKS,
                                                              Uz, Ur, zb, rhplane);
        k_gru_out<<<dim3(16, 16), 512, outk_lds, stream>>>(rhplane, wxb + (size_t)t * BKS,
                                                           Uh, zb, hplane, assign + (size_t)t * BKS);
    }
    k_einsum<<<dim3(4, 8, 16), 256, ein_lds, stream>>>(x, assign, part);
    k_reduce<<<dim3(Bc * Kc), 256, 0, stream>>>(assign, part, centers, vlad, norm2);
    k_norms<<<dim3(Bc), 64, 0, stream>>>(norm2, scl);
    k_scale<<<dim3(256), 256, 0, stream>>>(vlad, scl, out);
}

// Round 9
// 506.547 us; speedup vs baseline: 1.5150x; 1.0464x over previous
//
#include <hip/hip_runtime.h>

#define Bc 16
#define Tc 16
#define Cc 512
#define Kc 64
#define Sc 196
#define KS (Kc*Sc)          // 12544
#define BKS (Bc*Kc*Sc)      // 200704
#define TBKS (Tc*BKS)       // 3211264
#define GFIN (16*64*512)    // 524288
#define PART_N (8*GFIN)     // 4194304
#define PL 288              // 18 rows * 16 cols per plane
#define PLB (Kc*PL)         // 18432 floats per b

__device__ __forceinline__ float sigmoid_f(float x) { return 1.f / (1.f + __expf(-x)); }
__device__ __forceinline__ float tanh_f(float x) { return 1.f - 2.f / (__expf(2.f * x) + 1.f); }

// neighbor-lane reads within 16-lane DPP rows; out-of-range -> 0 (bound_ctrl)
__device__ __forceinline__ float dpp_prev(float v) {   // lane i <- lane i-1
    return __int_as_float(__builtin_amdgcn_mov_dpp(__float_as_int(v), 0x111, 0xf, 0xf, true));
}
__device__ __forceinline__ float dpp_next(float v) {   // lane i <- lane i+1
    return __int_as_float(__builtin_amdgcn_mov_dpp(__float_as_int(v), 0x101, 0xf, 0xf, true));
}

// ---------------- transpose share_w: wt[c][k] = w[k][c] ----------------
__global__ __launch_bounds__(256) void k_transpose_w(const float* __restrict__ w, float* __restrict__ wt) {
    int idx = blockIdx.x * 256 + threadIdx.x;
    if (idx < Kc * Cc) {
        int k = idx & 63, c = idx >> 6;
        wt[idx] = w[k * Cc + c];
    }
}

// ---------------- conv1x1: 64-row chunks, reg-double-buffered X staging, W via s_load ----------------
__global__ __launch_bounds__(256) void k_conv1x1(const float* __restrict__ x, const float* __restrict__ wt,
                                                 const float* __restrict__ bias, float* __restrict__ wxb) {
    __shared__ float Xs[64][64];
    const int tid = threadIdx.x;
    const int gs0 = blockIdx.x * 64;
    const int kw = __builtin_amdgcn_readfirstlane((tid >> 6) << 4);
    const int lane = tid & 63;
    const int rbase = (tid >> 6) * 16;
    const int gs_c = gs0 + lane;
    const int n_c = gs_c / Sc, s_c = gs_c - n_c * Sc;
    const float* xcol = x + (size_t)n_c * (Cc * Sc) + s_c;

    float xr[16];
#pragma unroll
    for (int q = 0; q < 16; ++q) xr[q] = xcol[(size_t)(rbase + q) * Sc];
    float acc[16] = {};
    for (int c0 = 0; c0 < Cc; c0 += 64) {
        __syncthreads();
#pragma unroll
        for (int q = 0; q < 16; ++q) Xs[rbase + q][lane] = xr[q];
        __syncthreads();
        if (c0 + 64 < Cc) {
#pragma unroll
            for (int q = 0; q < 16; ++q) xr[q] = xcol[(size_t)(c0 + 64 + rbase + q) * Sc];
        }
#pragma unroll 8
        for (int cc = 0; cc < 64; ++cc) {
            const float xv = Xs[cc][lane];
            const float* wp = wt + (size_t)(c0 + cc) * Kc + kw;   // wave-uniform -> s_load
#pragma unroll
            for (int i = 0; i < 16; ++i) acc[i] += wp[i] * xv;
        }
    }
    const int t = n_c & 15, bb = n_c >> 4;
    float* op = wxb + (((size_t)t * Bc + bb) * Kc + kw) * Sc + s_c;
#pragma unroll
    for (int i = 0; i < 16; ++i)
        op[(size_t)i * Sc] = acc[i] + bias[kw + i];
}

// ---------------- GRU t=0: h0=0 -> h = (1-sig(wxb))*tanh(wxb); init planes (pads=0) ----------------
__global__ __launch_bounds__(64) void k_gru_t0(const float* __restrict__ wxb,
        float* __restrict__ hplane, float* __restrict__ rhplane, float* __restrict__ assign) {
    const int blk = blockIdx.x;             // b*64 + k
    const size_t pbase = (size_t)blk * PL;
    const size_t cbase = (size_t)blk * Sc;
    for (int i = threadIdx.x; i < PL; i += 64) {
        int y = i >> 4, xx = i & 15;
        float v = 0.f;
        if (y >= 2 && y <= 15 && xx >= 1 && xx <= 14) {
            int s = (y - 2) * 14 + (xx - 1);
            float pre = wxb[cbase + s];
            v = (1.f - sigmoid_f(pre)) * tanh_f(pre);
            assign[cbase + s] = v;
        }
        hplane[pbase + i] = v;
        rhplane[pbase + i] = 0.f;
    }
}

// ---------------- GRU gates: 512 thr = 8 waves x 8 ki; DPP edges; b128 epilogue ----------------
// LDS: plane [64][288] (72KB) + red [8 wv][8 set][256 px] (64KB)
__global__ __launch_bounds__(512) void k_gru_gates(const float* __restrict__ hplane,
        const float* __restrict__ wxb_t, const float* __restrict__ Uz, const float* __restrict__ Ur,
        float* __restrict__ zb, float* __restrict__ rhplane) {
    extern __shared__ float lds[];
    float* P = lds;
    float* red = lds + PLB;
    const int b = blockIdx.x;
    const int k0 = blockIdx.y * 4;
    const int tid = threadIdx.x;
    const int wv = __builtin_amdgcn_readfirstlane(tid >> 6);
    const int lane = tid & 63;

    // epilogue geometry: thread owns set = wv, px = lane*4 + j
    const int kkE = wv >> 1, gE = wv & 1;
    const int kE = k0 + kkE;
    const int yqE = lane >> 2;
    const int xb0 = (lane & 3) << 2;
    const bool rowV = (yqE >= 1 && yqE <= 14);
    const size_t cbase = ((size_t)b * Kc + kE) * Sc;
    float preE[4];
#pragma unroll
    for (int j = 0; j < 4; ++j) {
        const int xb = xb0 + j;
        const bool v = rowV && xb >= 1 && xb <= 14;
        preE[j] = v ? wxb_t[cbase + (yqE - 1) * 14 + (xb - 1)] : 0.f;
    }
    {   // linear plane staging
        const float4* src = (const float4*)(hplane + (size_t)b * PLB);
        float4* dst = (float4*)P;
#pragma unroll
        for (int it = 0; it < 9; ++it) dst[it * 512 + tid] = src[it * 512 + tid];
    }
    __syncthreads();

    const int yp = lane >> 2, xq = (lane & 3) << 2;
    const float* uzb = Uz + (size_t)k0 * 576 + wv * 72;
    const float* urb = Ur + (size_t)k0 * 576 + wv * 72;
    float acc[4][2][4] = {};
    const float* Pw = P + (size_t)(wv * 8) * PL + yp * 16 + xq;
#pragma unroll 2
    for (int ki8 = 0; ki8 < 8; ++ki8) {
        const float* pk = Pw + ki8 * PL;
#pragma unroll
        for (int dy = 0; dy < 3; ++dy) {
            float4 m = *(const float4*)(pk + dy * 16);
            float e0 = dpp_prev(m.w);   // col xq-1 (pad cols are 0 -> boundary-correct)
            float e4 = dpp_next(m.x);   // col xq+4
#pragma unroll
            for (int kk = 0; kk < 4; ++kk) {
                const float* wz = uzb + kk * 576 + ki8 * 9 + dy * 3;
                float c0 = wz[0], c1 = wz[1], c2 = wz[2];
                acc[kk][0][0] += c0*e0  + c1*m.x + c2*m.y;
                acc[kk][0][1] += c0*m.x + c1*m.y + c2*m.z;
                acc[kk][0][2] += c0*m.y + c1*m.z + c2*m.w;
                acc[kk][0][3] += c0*m.z + c1*m.w + c2*e4;
                const float* wr = urb + kk * 576 + ki8 * 9 + dy * 3;
                float d0 = wr[0], d1 = wr[1], d2 = wr[2];
                acc[kk][1][0] += d0*e0  + d1*m.x + d2*m.y;
                acc[kk][1][1] += d0*m.x + d1*m.y + d2*m.z;
                acc[kk][1][2] += d0*m.y + d1*m.z + d2*m.w;
                acc[kk][1][3] += d0*m.z + d1*m.w + d2*e4;
            }
        }
    }
    {   // dump: red[wv][set = kk*2+g][px = lane*4+j] -- b128, conflict-free
        float* rp = red + (size_t)wv * 2048 + lane * 4;
#pragma unroll
        for (int kk = 0; kk < 4; ++kk)
#pragma unroll
            for (int g = 0; g < 2; ++g)
                *(float4*)(rp + (kk * 2 + g) * 256) =
                    make_float4(acc[kk][g][0], acc[kk][g][1], acc[kk][g][2], acc[kk][g][3]);
    }
    __syncthreads();
    {   // epilogue: 8 b128 partial reads, then 4 outputs
        const float* rp = red + (size_t)wv * 256 + lane * 4;
        float4 s0 = make_float4(0.f, 0.f, 0.f, 0.f);
#pragma unroll
        for (int w8 = 0; w8 < 8; ++w8) {
            float4 v = *(const float4*)(rp + (size_t)w8 * 2048);
            s0.x += v.x; s0.y += v.y; s0.z += v.z; s0.w += v.w;
        }
        const float sj[4] = {s0.x, s0.y, s0.z, s0.w};
#pragma unroll
        for (int j = 0; j < 4; ++j) {
            const int xb = xb0 + j;
            if (rowV && xb >= 1 && xb <= 14) {
                const int s = (yqE - 1) * 14 + (xb - 1);
                float sv = sigmoid_f(preE[j] + sj[j]);
                if (gE == 0) {
                    zb[cbase + s] = sv;
                } else {
                    float hv = P[(size_t)kE * PL + (yqE + 1) * 16 + xb];
                    rhplane[(size_t)b * PLB + (size_t)kE * PL + (yqE + 1) * 16 + xb] = sv * hv;
                }
            }
        }
    }
}

// ---------------- GRU out: 512 thr = 8 waves x 8 ki; DPP edges; b128 epilogue ----------------
// LDS: plane 72KB + red [8 wv][4 kk][256 px] (32KB)
__global__ __launch_bounds__(512) void k_gru_out(const float* __restrict__ rhplane,
        const float* __restrict__ wxb_t, const float* __restrict__ Uh, const float* __restrict__ zb,
        float* __restrict__ hplane, float* __restrict__ assign_t) {
    extern __shared__ float lds[];
    float* P = lds;
    float* red = lds + PLB;
    const int b = blockIdx.x;
    const int k0 = blockIdx.y * 4;
    const int tid = threadIdx.x;
    const int wv = __builtin_amdgcn_readfirstlane(tid >> 6);
    const int lane = tid & 63;

    // epilogue: threads 0..255, set kk = tid>>6, px = lane*4+j
    const bool epi = (tid < 256);
    const int kkE = wv;                      // valid when epi
    const int kE = k0 + (kkE & 3);
    const int yqE = lane >> 2;
    const int xb0 = (lane & 3) << 2;
    const bool rowV = (yqE >= 1 && yqE <= 14);
    const size_t cbase = ((size_t)b * Kc + kE) * Sc;
    const size_t pbase = (size_t)b * PLB + (size_t)kE * PL + (yqE + 1) * 16;
    float preE[4], zvE[4], hpE[4];
    if (epi) {
#pragma unroll
        for (int j = 0; j < 4; ++j) {
            const int xb = xb0 + j;
            const bool v = rowV && xb >= 1 && xb <= 14;
            const size_t cs = cbase + (v ? (yqE - 1) * 14 + (xb - 1) : 0);
            preE[j] = v ? wxb_t[cs] : 0.f;
            zvE[j]  = v ? zb[cs] : 0.f;
            hpE[j]  = v ? hplane[pbase + xb] : 0.f;
        }
    }
    {
        const float4* src = (const float4*)(rhplane + (size_t)b * PLB);
        float4* dst = (float4*)P;
#pragma unroll
        for (int it = 0; it < 9; ++it) dst[it * 512 + tid] = src[it * 512 + tid];
    }
    __syncthreads();

    const int yp = lane >> 2, xq = (lane & 3) << 2;
    const float* uhb = Uh + (size_t)k0 * 576 + wv * 72;
    float acc[4][4] = {};
    const float* Pw = P + (size_t)(wv * 8) * PL + yp * 16 + xq;
#pragma unroll 2
    for (int ki8 = 0; ki8 < 8; ++ki8) {
        const float* pk = Pw + ki8 * PL;
#pragma unroll
        for (int dy = 0; dy < 3; ++dy) {
            float4 m = *(const float4*)(pk + dy * 16);
            float e0 = dpp_prev(m.w);
            float e4 = dpp_next(m.x);
#pragma unroll
            for (int kk = 0; kk < 4; ++kk) {
                const float* wh = uhb + kk * 576 + ki8 * 9 + dy * 3;
                float c0 = wh[0], c1 = wh[1], c2 = wh[2];
                acc[kk][0] += c0*e0  + c1*m.x + c2*m.y;
                acc[kk][1] += c0*m.x + c1*m.y + c2*m.z;
                acc[kk][2] += c0*m.y + c1*m.z + c2*m.w;
                acc[kk][3] += c0*m.z + c1*m.w + c2*e4;
            }
        }
    }
    {
        float* rp = red + (size_t)wv * 1024 + lane * 4;
#pragma unroll
        for (int kk = 0; kk < 4; ++kk)
            *(float4*)(rp + kk * 256) = make_float4(acc[kk][0], acc[kk][1], acc[kk][2], acc[kk][3]);
    }
    __syncthreads();
    if (epi) {
        const float* rp = red + (size_t)(kkE & 3) * 256 + lane * 4;
        float4 s0 = make_float4(0.f, 0.f, 0.f, 0.f);
#pragma unroll
        for (int w8 = 0; w8 < 8; ++w8) {
            float4 v = *(const float4*)(rp + (size_t)w8 * 1024);
            s0.x += v.x; s0.y += v.y; s0.z += v.z; s0.w += v.w;
        }
        const float sj[4] = {s0.x, s0.y, s0.z, s0.w};
#pragma unroll
        for (int j = 0; j < 4; ++j) {
            const int xb = xb0 + j;
            if (rowV && xb >= 1 && xb <= 14) {
                const int s = (yqE - 1) * 14 + (xb - 1);
                float hh = tanh_f(preE[j] + sj[j]);
                float hn = (1.f - zvE[j]) * hh + zvE[j] * hpE[j];
                hplane[pbase + xb] = hn;
                assign_t[cbase + s] = hn;
            }
        }
    }
}

// ---------------- einsum: grid (4 ch,8 tg,16 b), 256 thr, 68KB LDS ----------------
__global__ __launch_bounds__(256) void k_einsum(const float* __restrict__ x, const float* __restrict__ assign,
                                                float* __restrict__ part) {
    extern __shared__ float lds[];
    float* As = lds;                 // [196][68]
    float* Xs = lds + 196 * 68;      // [28][132]
    const int ch = blockIdx.x, tg = blockIdx.y, b = blockIdx.z;
    const int tid = threadIdx.x;
    const int w = tid >> 6, lane = tid & 63;
    const int kt3 = lane >> 3, ct3 = lane & 7;
    const int kbase = kt3 * 8;
    const int cbase = w * 32 + ct3 * 4;
    float4 acc[8] = {};
    for (int tt = 0; tt < 2; ++tt) {
        const int t = tg * 2 + tt;
        const int n = b * Tc + t;
        __syncthreads();
        {
            const float* ap = assign + ((size_t)t * Bc + b) * KS;
            for (int q = tid; q < 3136; q += 256) {
                int kq = q / Sc, s = q - kq * Sc;
                int k4 = kq * 4;
                float4 v;
                v.x = ap[(size_t)(k4 + 0) * Sc + s];
                v.y = ap[(size_t)(k4 + 1) * Sc + s];
                v.z = ap[(size_t)(k4 + 2) * Sc + s];
                v.w = ap[(size_t)(k4 + 3) * Sc + s];
                *(float4*)(As + (size_t)s * 68 + k4) = v;
            }
        }
        for (int sc = 0; sc < 7; ++sc) {
            const int sb = sc * 28;
            __syncthreads();
            {
                const int c = tid & 127, sh = tid >> 7;
                const float* xp = x + ((size_t)n * Cc + ch * 128 + c) * Sc + sb + sh * 16;
                const int nf = sh ? 3 : 4;
                for (int f = 0; f < nf; ++f) {
                    float4 v = *(const float4*)(xp + f * 4);
                    float* dst = Xs + (size_t)(sh * 16 + f * 4) * 132 + c;
                    dst[0] = v.x; dst[132] = v.y; dst[264] = v.z; dst[396] = v.w;
                }
            }
            __syncthreads();
#pragma unroll 4
            for (int s = 0; s < 28; ++s) {
                const float* ap = As + (size_t)(sb + s) * 68 + kbase;
                float4 a0 = *(const float4*)ap;
                float4 a1 = *(const float4*)(ap + 4);
                float4 xv = *(const float4*)(Xs + (size_t)s * 132 + cbase);
                float av[8] = {a0.x,a0.y,a0.z,a0.w,a1.x,a1.y,a1.z,a1.w};
#pragma unroll
                for (int i = 0; i < 8; ++i) {
                    acc[i].x += av[i] * xv.x;
                    acc[i].y += av[i] * xv.y;
                    acc[i].z += av[i] * xv.z;
                    acc[i].w += av[i] * xv.w;
                }
            }
        }
    }
#pragma unroll
    for (int i = 0; i < 8; ++i) {
        const int k = kbase + i;
        float* op = part + (((size_t)tg * Bc + b) * Kc + k) * Cc + ch * 128 + cbase;
        *(float4*)op = acc[i];
    }
}

// ---------------- reduce: per (b,k): asum + partial-sum + center-subtract + sumsq ----------------
__global__ __launch_bounds__(256) void k_reduce(const float* __restrict__ assign, const float* __restrict__ part,
        const float* __restrict__ centers, float* __restrict__ vlad, float* __restrict__ norm2) {
    __shared__ float redw[4];
    __shared__ float a_s;
    const int blk = blockIdx.x;
    const int b = blk >> 6, k = blk & 63;
    const int tid = threadIdx.x;
    const int wave = tid >> 6, lane = tid & 63;
    const size_t bkoff = ((size_t)b * Kc + k) * Sc;
    float s = 0.f;
    for (int q = tid; q < 784; q += 256) {
        int t = q / 49, s4 = q - t * 49;
        float4 v = *(const float4*)(assign + (size_t)t * BKS + bkoff + s4 * 4);
        s += (v.x + v.y) + (v.z + v.w);
    }
#pragma unroll
    for (int o = 1; o < 64; o <<= 1) s += __shfl_xor(s, o);
    if (lane == 0) redw[wave] = s;
    __syncthreads();
    if (tid == 0) a_s = redw[0] + redw[1] + redw[2] + redw[3];
    __syncthreads();
    const float a = a_s;
    const size_t base = ((size_t)b * Kc + k) * Cc;
    const int c = tid * 2;
    float2 acc2 = make_float2(0.f, 0.f);
#pragma unroll
    for (int g = 0; g < 8; ++g) {
        float2 p = *(const float2*)(part + (size_t)g * GFIN + base + c);
        acc2.x += p.x; acc2.y += p.y;
    }
    float2 cv = *(const float2*)(centers + (size_t)k * Cc + c);
    float v0 = acc2.x - a * cv.x, v1 = acc2.y - a * cv.y;
    *(float2*)(vlad + base + c) = make_float2(v0, v1);
    float ss = v0 * v0 + v1 * v1;
#pragma unroll
    for (int o = 1; o < 64; o <<= 1) ss += __shfl_xor(ss, o);
    __syncthreads();
    if (lane == 0) redw[wave] = ss;
    __syncthreads();
    if (tid == 0) norm2[blk] = redw[0] + redw[1] + redw[2] + redw[3];
}

// ---------------- norms ----------------
__global__ __launch_bounds__(64) void k_norms(const float* __restrict__ norm2, float* __restrict__ scl) {
    const int b = blockIdx.x;
    const int k = threadIdx.x;
    float ss = norm2[b * Kc + k];
    float inv = 1.f / fmaxf(sqrtf(ss), 1e-12f);
    float g = ss * inv * inv;
#pragma unroll
    for (int o = 1; o < 64; o <<= 1) g += __shfl_xor(g, o);
    float gi = 1.f / fmaxf(sqrtf(g), 1e-12f);
    scl[b * Kc + k] = inv * gi;
}

// ---------------- scale ----------------
__global__ __launch_bounds__(256) void k_scale(const float* __restrict__ vlad, const float* __restrict__ scl,
                                               float* __restrict__ out) {
    const int blk = blockIdx.x;           // b*16 + kt
    const int b = blk >> 4, kt = blk & 15;
    const int tid = threadIdx.x;
    const int kk = tid >> 6, lane = tid & 63;
    const int k = kt * 4 + kk;
    const float sv = scl[b * Kc + k];
    const float* vp = vlad + ((size_t)b * Kc + k) * Cc + lane * 8;
    float* op = out + ((size_t)b * Kc + k) * Cc + lane * 8;
    float4 v0 = *(const float4*)vp;
    float4 v1 = *(const float4*)(vp + 4);
    *(float4*)op = make_float4(v0.x * sv, v0.y * sv, v0.z * sv, v0.w * sv);
    *(float4*)(op + 4) = make_float4(v1.x * sv, v1.y * sv, v1.z * sv, v1.w * sv);
}

extern "C" void kernel_launch(void* const* d_in, const int* in_sizes, int n_in,
                              void* d_out, int out_size, void* d_ws, size_t ws_size,
                              hipStream_t stream) {
    (void)in_sizes; (void)n_in; (void)out_size; (void)ws_size;
    const float* x       = (const float*)d_in[0];
    const float* centers = (const float*)d_in[1];
    const float* share_w = (const float*)d_in[2];
    const float* share_b = (const float*)d_in[3];
    const float* Uz      = (const float*)d_in[4];
    const float* Ur      = (const float*)d_in[5];
    const float* Uh      = (const float*)d_in[6];
    float* out = (float*)d_out;
    float* ws  = (float*)d_ws;

    float* part    = ws;
    float* vlad    = ws;
    float* wxb     = ws;
    float* rhplane = ws + (size_t)TBKS;
    float* assign  = ws + (size_t)PART_N;
    float* zb      = assign + (size_t)TBKS;
    float* hplane  = zb + (size_t)BKS;
    float* wt      = hplane + (size_t)Bc * PLB;
    float* norm2   = wt + (size_t)Kc * Cc;
    float* scl     = norm2 + (size_t)Bc * Kc;

    const size_t gates_lds = (size_t)(PLB + 8 * 8 * 256) * 4;   // 136 KB
    const size_t outk_lds  = (size_t)(PLB + 8 * 4 * 256) * 4;   // 104 KB
    const size_t ein_lds   = (size_t)(196 * 68 + 28 * 132) * 4; // 68.1 KB

    k_transpose_w<<<dim3(128), 256, 0, stream>>>(share_w, wt);
    k_conv1x1<<<dim3(784), 256, 0, stream>>>(x, wt, share_b, wxb);
    k_gru_t0<<<dim3(1024), 64, 0, stream>>>(wxb, hplane, rhplane, assign);
    for (int t = 1; t < Tc; ++t) {
        k_gru_gates<<<dim3(16, 16), 512, gates_lds, stream>>>(hplane, wxb + (size_t)t * BKS,
                                                              Uz, Ur, zb, rhplane);
        k_gru_out<<<dim3(16, 16), 512, outk_lds, stream>>>(rhplane, wxb + (size_t)t * BKS,
                                                           Uh, zb, hplane, assign + (size_t)t * BKS);
    }
    k_einsum<<<dim3(4, 8, 16), 256, ein_lds, stream>>>(x, assign, part);
    k_reduce<<<dim3(Bc * Kc), 256, 0, stream>>>(assign, part, centers, vlad, norm2);
    k_norms<<<dim3(Bc), 64, 0, stream>>>(norm2, scl);
    k_scale<<<dim3(256), 256, 0, stream>>>(vlad, scl, out);
}

// Round 10
// 464.619 us; speedup vs baseline: 1.6517x; 1.0902x over previous
//
#include <hip/hip_runtime.h>

#define Bc 16
#define Tc 16
#define Cc 512
#define Kc 64
#define Sc 196
#define KS (Kc*Sc)          // 12544
#define BKS (Bc*Kc*Sc)      // 200704
#define TBKS (Tc*BKS)       // 3211264
#define GFIN (16*64*512)    // 524288
#define PART_N (8*GFIN)     // 4194304
#define PX 256              // 16 rows * 16 cols per plane
#define PLB2 (Kc*PX)        // 16384 floats per b

__device__ __forceinline__ float sigmoid_f(float x) { return 1.f / (1.f + __expf(-x)); }
__device__ __forceinline__ float tanh_f(float x) { return 1.f - 2.f / (__expf(2.f * x) + 1.f); }

// neighbor-lane reads within 16-lane DPP rows; out-of-range -> 0 (bound_ctrl)
__device__ __forceinline__ float dpp_prev(float v) {   // lane i <- lane i-1
    return __int_as_float(__builtin_amdgcn_mov_dpp(__float_as_int(v), 0x111, 0xf, 0xf, true));
}
__device__ __forceinline__ float dpp_next(float v) {   // lane i <- lane i+1
    return __int_as_float(__builtin_amdgcn_mov_dpp(__float_as_int(v), 0x101, 0xf, 0xf, true));
}

// ---------------- transpose share_w: wt[c][k] = w[k][c] ----------------
__global__ __launch_bounds__(256) void k_transpose_w(const float* __restrict__ w, float* __restrict__ wt) {
    int idx = blockIdx.x * 256 + threadIdx.x;
    if (idx < Kc * Cc) {
        int k = idx & 63, c = idx >> 6;
        wt[idx] = w[k * Cc + c];
    }
}

// ---------------- conv1x1: 64-row chunks, reg-double-buffered X staging, W via s_load ----------------
__global__ __launch_bounds__(256) void k_conv1x1(const float* __restrict__ x, const float* __restrict__ wt,
                                                 const float* __restrict__ bias, float* __restrict__ wxb) {
    __shared__ float Xs[64][64];
    const int tid = threadIdx.x;
    const int gs0 = blockIdx.x * 64;
    const int kw = __builtin_amdgcn_readfirstlane((tid >> 6) << 4);
    const int lane = tid & 63;
    const int rbase = (tid >> 6) * 16;
    const int gs_c = gs0 + lane;
    const int n_c = gs_c / Sc, s_c = gs_c - n_c * Sc;
    const float* xcol = x + (size_t)n_c * (Cc * Sc) + s_c;

    float xr[16];
#pragma unroll
    for (int q = 0; q < 16; ++q) xr[q] = xcol[(size_t)(rbase + q) * Sc];
    float acc[16] = {};
    for (int c0 = 0; c0 < Cc; c0 += 64) {
        __syncthreads();
#pragma unroll
        for (int q = 0; q < 16; ++q) Xs[rbase + q][lane] = xr[q];
        __syncthreads();
        if (c0 + 64 < Cc) {
#pragma unroll
            for (int q = 0; q < 16; ++q) xr[q] = xcol[(size_t)(c0 + 64 + rbase + q) * Sc];
        }
#pragma unroll 8
        for (int cc = 0; cc < 64; ++cc) {
            const float xv = Xs[cc][lane];
            const float* wp = wt + (size_t)(c0 + cc) * Kc + kw;   // wave-uniform -> s_load
#pragma unroll
            for (int i = 0; i < 16; ++i) acc[i] += wp[i] * xv;
        }
    }
    const int t = n_c & 15, bb = n_c >> 4;
    float* op = wxb + (((size_t)t * Bc + bb) * Kc + kw) * Sc + s_c;
#pragma unroll
    for (int i = 0; i < 16; ++i)
        op[(size_t)i * Sc] = acc[i] + bias[kw + i];
}

// ---------------- GRU t=0: h0=0 -> h = (1-sig(wxb))*tanh(wxb); init 16-row planes ----------------
__global__ __launch_bounds__(64) void k_gru_t0(const float* __restrict__ wxb,
        float* __restrict__ hplane, float* __restrict__ rhplane, float* __restrict__ assign) {
    const int blk = blockIdx.x;             // b*64 + k
    const size_t pbase = (size_t)blk * PX;
    const size_t cbase = (size_t)blk * Sc;
    for (int i = threadIdx.x; i < PX; i += 64) {
        int row = i >> 4, col = i & 15;
        float v = 0.f;
        if (row >= 1 && row <= 14 && col >= 1 && col <= 14) {
            int s = (row - 1) * 14 + (col - 1);
            float pre = wxb[cbase + s];
            v = (1.f - sigmoid_f(pre)) * tanh_f(pre);
            assign[cbase + s] = v;
        }
        hplane[pbase + i] = v;
        rhplane[pbase + i] = 0.f;
    }
}

// ---------------- GRU gates: grid (16 b, 64 k), 512 thr = 8 waves x 8 ki; 80KB LDS (2 blk/CU) ----------------
// LDS: plane [64][256] (64KB) + red [8 wv][2 g][256 px] (16KB)
__global__ __launch_bounds__(512) void k_gru_gates(const float* __restrict__ hplane,
        const float* __restrict__ wxb_t, const float* __restrict__ Uz, const float* __restrict__ Ur,
        float* __restrict__ zb, float* __restrict__ rhplane) {
    extern __shared__ float lds[];
    float* P = lds;
    float* red = lds + PLB2;
    const int b = blockIdx.x;
    const int k = blockIdx.y;
    const int tid = threadIdx.x;
    const int wv = __builtin_amdgcn_readfirstlane(tid >> 6);
    const int lane = tid & 63;

    // epilogue: thread owns (set = tid>>8, px = tid&255)
    const int setE = tid >> 8;
    const int pxE = tid & 255;
    const int rE = pxE >> 4, xbE = pxE & 15;
    const bool valE = (rE >= 1 && rE <= 14 && xbE >= 1 && xbE <= 14);
    const size_t cbase = ((size_t)b * Kc + k) * Sc;
    const int sE = (rE - 1) * 14 + (xbE - 1);
    const float preE = valE ? wxb_t[cbase + sE] : 0.f;

    {   // linear plane staging: 64KB
        const float4* src = (const float4*)(hplane + (size_t)b * PLB2);
        float4* dst = (float4*)P;
#pragma unroll
        for (int it = 0; it < 8; ++it) dst[it * 512 + tid] = src[it * 512 + tid];
    }
    __syncthreads();

    const int yp = lane >> 2, xq = (lane & 3) << 2;
    const int rowbase = (yp > 0) ? (yp - 1) : 0;     // yp=0 lanes are pad rows (discarded)
    const float* uzb = Uz + (size_t)k * 576 + wv * 72;
    const float* urb = Ur + (size_t)k * 576 + wv * 72;
    float az[4] = {}, ar[4] = {};
    const float* Pw = P + (size_t)(wv * 8) * PX + rowbase * 16 + xq;
#pragma unroll 2
    for (int ki8 = 0; ki8 < 8; ++ki8) {
        const float* pk = Pw + ki8 * PX;
#pragma unroll
        for (int dy = 0; dy < 3; ++dy) {
            float4 m = *(const float4*)(pk + dy * 16);
            float e0 = dpp_prev(m.w);   // pad cols are 0 -> boundary-correct
            float e4 = dpp_next(m.x);
            const float* wz = uzb + ki8 * 9 + dy * 3;
            float c0 = wz[0], c1 = wz[1], c2 = wz[2];
            az[0] += c0*e0  + c1*m.x + c2*m.y;
            az[1] += c0*m.x + c1*m.y + c2*m.z;
            az[2] += c0*m.y + c1*m.z + c2*m.w;
            az[3] += c0*m.z + c1*m.w + c2*e4;
            const float* wr = urb + ki8 * 9 + dy * 3;
            float d0 = wr[0], d1 = wr[1], d2 = wr[2];
            ar[0] += d0*e0  + d1*m.x + d2*m.y;
            ar[1] += d0*m.x + d1*m.y + d2*m.z;
            ar[2] += d0*m.y + d1*m.z + d2*m.w;
            ar[3] += d0*m.z + d1*m.w + d2*e4;
        }
    }
    {   // dump: red[wv][g][px], px = lane*4+j -- b128, conflict-free
        float* rp = red + (size_t)wv * 512 + lane * 4;
        *(float4*)rp = make_float4(az[0], az[1], az[2], az[3]);
        *(float4*)(rp + 256) = make_float4(ar[0], ar[1], ar[2], ar[3]);
    }
    __syncthreads();
    {   // reduce over 8 waves + write
        const float* q = red + setE * 256 + pxE;
        float s0 = 0.f;
#pragma unroll
        for (int w8 = 0; w8 < 8; ++w8) s0 += q[(size_t)w8 * 512];
        if (valE) {
            float sv = sigmoid_f(preE + s0);
            if (setE == 0) {
                zb[cbase + sE] = sv;
            } else {
                float hv = P[(size_t)k * PX + pxE];
                rhplane[(size_t)b * PLB2 + (size_t)k * PX + pxE] = sv * hv;
            }
        }
    }
}

// ---------------- GRU out: grid (16 b, 64 k), 512 thr; 72KB LDS (2 blk/CU) ----------------
// LDS: plane 64KB + red [8 wv][256 px] (8KB)
__global__ __launch_bounds__(512) void k_gru_out(const float* __restrict__ rhplane,
        const float* __restrict__ wxb_t, const float* __restrict__ Uh, const float* __restrict__ zb,
        float* __restrict__ hplane, float* __restrict__ assign_t) {
    extern __shared__ float lds[];
    float* P = lds;
    float* red = lds + PLB2;
    const int b = blockIdx.x;
    const int k = blockIdx.y;
    const int tid = threadIdx.x;
    const int wv = __builtin_amdgcn_readfirstlane(tid >> 6);
    const int lane = tid & 63;

    // epilogue: threads 0..255, px = tid
    const bool epi = (tid < 256);
    const int pxE = tid & 255;
    const int rE = pxE >> 4, xbE = pxE & 15;
    const bool valE = epi && (rE >= 1 && rE <= 14 && xbE >= 1 && xbE <= 14);
    const size_t cbase = ((size_t)b * Kc + k) * Sc;
    const size_t pbase = (size_t)b * PLB2 + (size_t)k * PX;
    const int sE = (rE - 1) * 14 + (xbE - 1);
    float preE = 0.f, zvE = 0.f, hpE = 0.f;
    if (valE) {
        preE = wxb_t[cbase + sE];
        zvE = zb[cbase + sE];
        hpE = hplane[pbase + pxE];
    }
    {
        const float4* src = (const float4*)(rhplane + (size_t)b * PLB2);
        float4* dst = (float4*)P;
#pragma unroll
        for (int it = 0; it < 8; ++it) dst[it * 512 + tid] = src[it * 512 + tid];
    }
    __syncthreads();

    const int yp = lane >> 2, xq = (lane & 3) << 2;
    const int rowbase = (yp > 0) ? (yp - 1) : 0;
    const float* uhb = Uh + (size_t)k * 576 + wv * 72;
    float ah[4] = {};
    const float* Pw = P + (size_t)(wv * 8) * PX + rowbase * 16 + xq;
#pragma unroll 2
    for (int ki8 = 0; ki8 < 8; ++ki8) {
        const float* pk = Pw + ki8 * PX;
#pragma unroll
        for (int dy = 0; dy < 3; ++dy) {
            float4 m = *(const float4*)(pk + dy * 16);
            float e0 = dpp_prev(m.w);
            float e4 = dpp_next(m.x);
            const float* wh = uhb + ki8 * 9 + dy * 3;
            float c0 = wh[0], c1 = wh[1], c2 = wh[2];
            ah[0] += c0*e0  + c1*m.x + c2*m.y;
            ah[1] += c0*m.x + c1*m.y + c2*m.z;
            ah[2] += c0*m.y + c1*m.z + c2*m.w;
            ah[3] += c0*m.z + c1*m.w + c2*e4;
        }
    }
    {
        float* rp = red + (size_t)wv * 256 + lane * 4;
        *(float4*)rp = make_float4(ah[0], ah[1], ah[2], ah[3]);
    }
    __syncthreads();
    if (epi) {
        const float* q = red + pxE;
        float s0 = 0.f;
#pragma unroll
        for (int w8 = 0; w8 < 8; ++w8) s0 += q[(size_t)w8 * 256];
        if (valE) {
            float hh = tanh_f(preE + s0);
            float hn = (1.f - zvE) * hh + zvE * hpE;
            hplane[pbase + pxE] = hn;
            assign_t[cbase + sE] = hn;
        }
    }
}

// ---------------- einsum: grid (4 ch,8 tg,16 b), 256 thr, 68KB LDS ----------------
__global__ __launch_bounds__(256) void k_einsum(const float* __restrict__ x, const float* __restrict__ assign,
                                                float* __restrict__ part) {
    extern __shared__ float lds[];
    float* As = lds;                 // [196][68]
    float* Xs = lds + 196 * 68;      // [28][132]
    const int ch = blockIdx.x, tg = blockIdx.y, b = blockIdx.z;
    const int tid = threadIdx.x;
    const int w = tid >> 6, lane = tid & 63;
    const int kt3 = lane >> 3, ct3 = lane & 7;
    const int kbase = kt3 * 8;
    const int cbase = w * 32 + ct3 * 4;
    float4 acc[8] = {};
    for (int tt = 0; tt < 2; ++tt) {
        const int t = tg * 2 + tt;
        const int n = b * Tc + t;
        __syncthreads();
        {
            const float* ap = assign + ((size_t)t * Bc + b) * KS;
            for (int q = tid; q < 3136; q += 256) {
                int kq = q / Sc, s = q - kq * Sc;
                int k4 = kq * 4;
                float4 v;
                v.x = ap[(size_t)(k4 + 0) * Sc + s];
                v.y = ap[(size_t)(k4 + 1) * Sc + s];
                v.z = ap[(size_t)(k4 + 2) * Sc + s];
                v.w = ap[(size_t)(k4 + 3) * Sc + s];
                *(float4*)(As + (size_t)s * 68 + k4) = v;
            }
        }
        for (int sc = 0; sc < 7; ++sc) {
            const int sb = sc * 28;
            __syncthreads();
            {
                const int c = tid & 127, sh = tid >> 7;
                const float* xp = x + ((size_t)n * Cc + ch * 128 + c) * Sc + sb + sh * 16;
                const int nf = sh ? 3 : 4;
                for (int f = 0; f < nf; ++f) {
                    float4 v = *(const float4*)(xp + f * 4);
                    float* dst = Xs + (size_t)(sh * 16 + f * 4) * 132 + c;
                    dst[0] = v.x; dst[132] = v.y; dst[264] = v.z; dst[396] = v.w;
                }
            }
            __syncthreads();
#pragma unroll 4
            for (int s = 0; s < 28; ++s) {
                const float* ap = As + (size_t)(sb + s) * 68 + kbase;
                float4 a0 = *(const float4*)ap;
                float4 a1 = *(const float4*)(ap + 4);
                float4 xv = *(const float4*)(Xs + (size_t)s * 132 + cbase);
                float av[8] = {a0.x,a0.y,a0.z,a0.w,a1.x,a1.y,a1.z,a1.w};
#pragma unroll
                for (int i = 0; i < 8; ++i) {
                    acc[i].x += av[i] * xv.x;
                    acc[i].y += av[i] * xv.y;
                    acc[i].z += av[i] * xv.z;
                    acc[i].w += av[i] * xv.w;
                }
            }
        }
    }
#pragma unroll
    for (int i = 0; i < 8; ++i) {
        const int k = kbase + i;
        float* op = part + (((size_t)tg * Bc + b) * Kc + k) * Cc + ch * 128 + cbase;
        *(float4*)op = acc[i];
    }
}

// ---------------- reduce: per (b,k): asum + partial-sum + center-subtract + sumsq ----------------
__global__ __launch_bounds__(256) void k_reduce(const float* __restrict__ assign, const float* __restrict__ part,
        const float* __restrict__ centers, float* __restrict__ vlad, float* __restrict__ norm2) {
    __shared__ float redw[4];
    __shared__ float a_s;
    const int blk = blockIdx.x;
    const int b = blk >> 6, k = blk & 63;
    const int tid = threadIdx.x;
    const int wave = tid >> 6, lane = tid & 63;
    const size_t bkoff = ((size_t)b * Kc + k) * Sc;
    float s = 0.f;
    for (int q = tid; q < 784; q += 256) {
        int t = q / 49, s4 = q - t * 49;
        float4 v = *(const float4*)(assign + (size_t)t * BKS + bkoff + s4 * 4);
        s += (v.x + v.y) + (v.z + v.w);
    }
#pragma unroll
    for (int o = 1; o < 64; o <<= 1) s += __shfl_xor(s, o);
    if (lane == 0) redw[wave] = s;
    __syncthreads();
    if (tid == 0) a_s = redw[0] + redw[1] + redw[2] + redw[3];
    __syncthreads();
    const float a = a_s;
    const size_t base = ((size_t)b * Kc + k) * Cc;
    const int c = tid * 2;
    float2 acc2 = make_float2(0.f, 0.f);
#pragma unroll
    for (int g = 0; g < 8; ++g) {
        float2 p = *(const float2*)(part + (size_t)g * GFIN + base + c);
        acc2.x += p.x; acc2.y += p.y;
    }
    float2 cv = *(const float2*)(centers + (size_t)k * Cc + c);
    float v0 = acc2.x - a * cv.x, v1 = acc2.y - a * cv.y;
    *(float2*)(vlad + base + c) = make_float2(v0, v1);
    float ss = v0 * v0 + v1 * v1;
#pragma unroll
    for (int o = 1; o < 64; o <<= 1) ss += __shfl_xor(ss, o);
    __syncthreads();
    if (lane == 0) redw[wave] = ss;
    __syncthreads();
    if (tid == 0) norm2[blk] = redw[0] + redw[1] + redw[2] + redw[3];
}

// ---------------- norms ----------------
__global__ __launch_bounds__(64) void k_norms(const float* __restrict__ norm2, float* __restrict__ scl) {
    const int b = blockIdx.x;
    const int k = threadIdx.x;
    float ss = norm2[b * Kc + k];
    float inv = 1.f / fmaxf(sqrtf(ss), 1e-12f);
    float g = ss * inv * inv;
#pragma unroll
    for (int o = 1; o < 64; o <<= 1) g += __shfl_xor(g, o);
    float gi = 1.f / fmaxf(sqrtf(g), 1e-12f);
    scl[b * Kc + k] = inv * gi;
}

// ---------------- scale ----------------
__global__ __launch_bounds__(256) void k_scale(const float* __restrict__ vlad, const float* __restrict__ scl,
                                               float* __restrict__ out) {
    const int blk = blockIdx.x;           // b*16 + kt
    const int b = blk >> 4, kt = blk & 15;
    const int tid = threadIdx.x;
    const int kk = tid >> 6, lane = tid & 63;
    const int k = kt * 4 + kk;
    const float sv = scl[b * Kc + k];
    const float* vp = vlad + ((size_t)b * Kc + k) * Cc + lane * 8;
    float* op = out + ((size_t)b * Kc + k) * Cc + lane * 8;
    float4 v0 = *(const float4*)vp;
    float4 v1 = *(const float4*)(vp + 4);
    *(float4*)op = make_float4(v0.x * sv, v0.y * sv, v0.z * sv, v0.w * sv);
    *(float4*)(op + 4) = make_float4(v1.x * sv, v1.y * sv, v1.z * sv, v1.w * sv);
}

extern "C" void kernel_launch(void* const* d_in, const int* in_sizes, int n_in,
                              void* d_out, int out_size, void* d_ws, size_t ws_size,
                              hipStream_t stream) {
    (void)in_sizes; (void)n_in; (void)out_size; (void)ws_size;
    const float* x       = (const float*)d_in[0];
    const float* centers = (const float*)d_in[1];
    const float* share_w = (const float*)d_in[2];
    const float* share_b = (const float*)d_in[3];
    const float* Uz      = (const float*)d_in[4];
    const float* Ur      = (const float*)d_in[5];
    const float* Uh      = (const float*)d_in[6];
    float* out = (float*)d_out;
    float* ws  = (float*)d_ws;

    float* part    = ws;
    float* vlad    = ws;
    float* wxb     = ws;
    float* rhplane = ws + (size_t)TBKS;              // [B][64][256] = 262144 floats
    float* assign  = ws + (size_t)PART_N;
    float* zb      = assign + (size_t)TBKS;
    float* hplane  = zb + (size_t)BKS;               // [B][64][256]
    float* wt      = hplane + (size_t)Bc * PLB2;
    float* norm2   = wt + (size_t)Kc * Cc;
    float* scl     = norm2 + (size_t)Bc * Kc;

    const size_t gates_lds = (size_t)(PLB2 + 8 * 2 * 256) * 4;  // 80 KB exactly
    const size_t outk_lds  = (size_t)(PLB2 + 8 * 256) * 4;      // 72 KB
    const size_t ein_lds   = (size_t)(196 * 68 + 28 * 132) * 4; // 68.1 KB

    k_transpose_w<<<dim3(128), 256, 0, stream>>>(share_w, wt);
    k_conv1x1<<<dim3(784), 256, 0, stream>>>(x, wt, share_b, wxb);
    k_gru_t0<<<dim3(1024), 64, 0, stream>>>(wxb, hplane, rhplane, assign);
    for (int t = 1; t < Tc; ++t) {
        k_gru_gates<<<dim3(16, 64), 512, gates_lds, stream>>>(hplane, wxb + (size_t)t * BKS,
                                                              Uz, Ur, zb, rhplane);
        k_gru_out<<<dim3(16, 64), 512, outk_lds, stream>>>(rhplane, wxb + (size_t)t * BKS,
                                                           Uh, zb, hplane, assign + (size_t)t * BKS);
    }
    k_einsum<<<dim3(4, 8, 16), 256, ein_lds, stream>>>(x, assign, part);
    k_reduce<<<dim3(Bc * Kc), 256, 0, stream>>>(assign, part, centers, vlad, norm2);
    k_norms<<<dim3(Bc), 64, 0, stream>>>(norm2, scl);
    k_scale<<<dim3(256), 256, 0, stream>>>(vlad, scl, out);
}

// Round 11
// 459.301 us; speedup vs baseline: 1.6708x; 1.0116x over previous
//
#include <hip/hip_runtime.h>

#define Bc 16
#define Tc 16
#define Cc 512
#define Kc 64
#define Sc 196
#define KS (Kc*Sc)          // 12544
#define BKS (Bc*Kc*Sc)      // 200704
#define TBKS (Tc*BKS)       // 3211264
#define GFIN (16*64*512)    // 524288
#define PART_N (8*GFIN)     // 4194304
#define PX 256              // 16 rows * 16 cols per plane
#define PLB2 (Kc*PX)        // 16384 elems per b

__device__ __forceinline__ float sigmoid_f(float x) { return 1.f / (1.f + __expf(-x)); }
__device__ __forceinline__ float tanh_f(float x) { return 1.f - 2.f / (__expf(2.f * x) + 1.f); }

__device__ __forceinline__ float b2f(unsigned short u) {
    return __uint_as_float(((unsigned)u) << 16);
}
__device__ __forceinline__ unsigned short f2b(float f) {   // RNE
    unsigned u = __float_as_uint(f);
    return (unsigned short)((u + 0x7FFFu + ((u >> 16) & 1u)) >> 16);
}

// neighbor-lane reads within 16-lane DPP rows; out-of-range -> 0 (bound_ctrl)
__device__ __forceinline__ float dpp_prev(float v) {   // lane i <- lane i-1
    return __int_as_float(__builtin_amdgcn_mov_dpp(__float_as_int(v), 0x111, 0xf, 0xf, true));
}
__device__ __forceinline__ float dpp_next(float v) {   // lane i <- lane i+1
    return __int_as_float(__builtin_amdgcn_mov_dpp(__float_as_int(v), 0x101, 0xf, 0xf, true));
}

// ---------------- transpose share_w: wt[c][k] = w[k][c] ----------------
__global__ __launch_bounds__(256) void k_transpose_w(const float* __restrict__ w, float* __restrict__ wt) {
    int idx = blockIdx.x * 256 + threadIdx.x;
    if (idx < Kc * Cc) {
        int k = idx & 63, c = idx >> 6;
        wt[idx] = w[k * Cc + c];
    }
}

// ---------------- conv1x1: 64-row chunks, reg-double-buffered X staging, W via s_load ----------------
__global__ __launch_bounds__(256) void k_conv1x1(const float* __restrict__ x, const float* __restrict__ wt,
                                                 const float* __restrict__ bias, float* __restrict__ wxb) {
    __shared__ float Xs[64][64];
    const int tid = threadIdx.x;
    const int gs0 = blockIdx.x * 64;
    const int kw = __builtin_amdgcn_readfirstlane((tid >> 6) << 4);
    const int lane = tid & 63;
    const int rbase = (tid >> 6) * 16;
    const int gs_c = gs0 + lane;
    const int n_c = gs_c / Sc, s_c = gs_c - n_c * Sc;
    const float* xcol = x + (size_t)n_c * (Cc * Sc) + s_c;

    float xr[16];
#pragma unroll
    for (int q = 0; q < 16; ++q) xr[q] = xcol[(size_t)(rbase + q) * Sc];
    float acc[16] = {};
    for (int c0 = 0; c0 < Cc; c0 += 64) {
        __syncthreads();
#pragma unroll
        for (int q = 0; q < 16; ++q) Xs[rbase + q][lane] = xr[q];
        __syncthreads();
        if (c0 + 64 < Cc) {
#pragma unroll
            for (int q = 0; q < 16; ++q) xr[q] = xcol[(size_t)(c0 + 64 + rbase + q) * Sc];
        }
#pragma unroll 8
        for (int cc = 0; cc < 64; ++cc) {
            const float xv = Xs[cc][lane];
            const float* wp = wt + (size_t)(c0 + cc) * Kc + kw;   // wave-uniform -> s_load
#pragma unroll
            for (int i = 0; i < 16; ++i) acc[i] += wp[i] * xv;
        }
    }
    const int t = n_c & 15, bb = n_c >> 4;
    float* op = wxb + (((size_t)t * Bc + bb) * Kc + kw) * Sc + s_c;
#pragma unroll
    for (int i = 0; i < 16; ++i)
        op[(size_t)i * Sc] = acc[i] + bias[kw + i];
}

// ---------------- GRU t=0: h0=0 -> h = (1-sig(wxb))*tanh(wxb); init planes ----------------
__global__ __launch_bounds__(64) void k_gru_t0(const float* __restrict__ wxb,
        float* __restrict__ hplane32, unsigned short* __restrict__ hplane16,
        unsigned short* __restrict__ rhplane16, float* __restrict__ assign) {
    const int blk = blockIdx.x;             // b*64 + k
    const size_t pbase = (size_t)blk * PX;
    const size_t cbase = (size_t)blk * Sc;
    for (int i = threadIdx.x; i < PX; i += 64) {
        int row = i >> 4, col = i & 15;
        float v = 0.f;
        if (row >= 1 && row <= 14 && col >= 1 && col <= 14) {
            int s = (row - 1) * 14 + (col - 1);
            float pre = wxb[cbase + s];
            v = (1.f - sigmoid_f(pre)) * tanh_f(pre);
            assign[cbase + s] = v;
        }
        hplane32[pbase + i] = v;
        hplane16[pbase + i] = f2b(v);
        rhplane16[pbase + i] = 0;
    }
}

// ---------------- GRU gates: grid (16 b, 16 kt), 512 thr = 8 waves = (kp 2) x (kiq 4) ----------------
// LDS: plane bf16 [64][256] (32KB) + red fp32 [8 wv][16 v][64 lane] (32KB) = 64KB
__global__ __launch_bounds__(512) void k_gru_gates(const unsigned short* __restrict__ hplane16,
        const float* __restrict__ wxb_t, const float* __restrict__ Uz, const float* __restrict__ Ur,
        float* __restrict__ zb, unsigned short* __restrict__ rhplane16) {
    extern __shared__ float lds[];
    unsigned short* P = (unsigned short*)lds;   // [64][256] bf16
    float* red = lds + 8192;
    const int b = blockIdx.x;
    const int k0 = blockIdx.y * 4;
    const int tid = threadIdx.x;
    const int wv = __builtin_amdgcn_readfirstlane(tid >> 6);
    const int lane = tid & 63;
    const int kp = wv >> 2, kiq = wv & 3;

    // epilogue prefetch: 4 outputs, o = tid + q*512; set=o>>8: kp_o=set>>2, g=(set>>1)&1, r=set&1
    float preE[4]; bool valE[4]; size_t csE[4]; int kEa[4];
#pragma unroll
    for (int q = 0; q < 4; ++q) {
        const int o = tid + q * 512;
        const int set = o >> 8, px = o & 255;
        const int kp_o = set >> 2, r = set & 1;
        kEa[q] = k0 + kp_o * 2 + r;
        const int row = px >> 4, col = px & 15;
        valE[q] = (row >= 1 && row <= 14 && col >= 1 && col <= 14);
        csE[q] = ((size_t)b * Kc + kEa[q]) * Sc + (valE[q] ? (row - 1) * 14 + (col - 1) : 0);
        preE[q] = valE[q] ? wxb_t[csE[q]] : 0.f;
    }
    {   // stage plane: 32KB linear bf16 copy
        const float4* src = (const float4*)(hplane16 + (size_t)b * PLB2);
        float4* dst = (float4*)P;
#pragma unroll
        for (int it = 0; it < 4; ++it) dst[it * 512 + tid] = src[it * 512 + tid];
    }
    __syncthreads();

    const int yp = lane >> 2, xq = (lane & 3) << 2;
    const int rowbase = (yp > 0) ? (yp - 1) : 0;     // yp=0 lanes produce pad rows (discarded)
    const float* uz0 = Uz + (size_t)(k0 + kp * 2) * 576 + kiq * 144;
    const float* ur0 = Ur + (size_t)(k0 + kp * 2) * 576 + kiq * 144;
    float az[2][4] = {}, ar[2][4] = {};
    const unsigned short* Pw = P + (size_t)(kiq * 16) * PX + rowbase * 16 + xq;
#pragma unroll 2
    for (int ki = 0; ki < 16; ++ki) {
        const unsigned short* pk = Pw + ki * PX;
#pragma unroll
        for (int dy = 0; dy < 3; ++dy) {
            ushort4 u = *(const ushort4*)(pk + dy * 16);
            float4 m = make_float4(b2f(u.x), b2f(u.y), b2f(u.z), b2f(u.w));
            float e0 = dpp_prev(m.w);   // pad cols are 0 -> boundary-correct
            float e4 = dpp_next(m.x);
#pragma unroll
            for (int r = 0; r < 2; ++r) {
                const float* wz = uz0 + r * 576 + ki * 9 + dy * 3;
                float c0 = wz[0], c1 = wz[1], c2 = wz[2];
                az[r][0] += c0*e0  + c1*m.x + c2*m.y;
                az[r][1] += c0*m.x + c1*m.y + c2*m.z;
                az[r][2] += c0*m.y + c1*m.z + c2*m.w;
                az[r][3] += c0*m.z + c1*m.w + c2*e4;
                const float* wr = ur0 + r * 576 + ki * 9 + dy * 3;
                float d0 = wr[0], d1 = wr[1], d2 = wr[2];
                ar[r][0] += d0*e0  + d1*m.x + d2*m.y;
                ar[r][1] += d0*m.x + d1*m.y + d2*m.z;
                ar[r][2] += d0*m.y + d1*m.z + d2*m.w;
                ar[r][3] += d0*m.z + d1*m.w + d2*e4;
            }
        }
    }
    {   // dump red[wv][v][lane], v = (g*2+r)*4 + jj
        float* rp = red + (size_t)wv * 1024 + lane;
#pragma unroll
        for (int r = 0; r < 2; ++r)
#pragma unroll
            for (int jj = 0; jj < 4; ++jj) {
                rp[(size_t)(r * 4 + jj) * 64] = az[r][jj];
                rp[(size_t)(8 + r * 4 + jj) * 64] = ar[r][jj];
            }
    }
    __syncthreads();
#pragma unroll
    for (int q = 0; q < 4; ++q) {
        const int o = tid + q * 512;
        const int set = o >> 8, px = o & 255;
        const int kp_o = set >> 2, g = (set >> 1) & 1, r = set & 1;
        const int lane_r = ((px >> 4) << 2) + ((px & 15) >> 2);
        const int v = (g * 2 + r) * 4 + (px & 3);
        float s0 = 0.f;
#pragma unroll
        for (int kq2 = 0; kq2 < 4; ++kq2)
            s0 += red[(size_t)((kp_o * 4 + kq2) * 16 + v) * 64 + lane_r];
        if (valE[q]) {
            float sv = sigmoid_f(preE[q] + s0);
            if (g == 0) {
                zb[csE[q]] = sv;
            } else {
                float hv = b2f(P[(size_t)kEa[q] * PX + px]);
                rhplane16[(size_t)b * PLB2 + (size_t)kEa[q] * PX + px] = f2b(sv * hv);
            }
        }
    }
}

// ---------------- GRU out: grid (16 b, 16 kt), 512 thr; LDS 32KB plane + 16KB red = 48KB ----------------
__global__ __launch_bounds__(512) void k_gru_out(const unsigned short* __restrict__ rhplane16,
        const float* __restrict__ wxb_t, const float* __restrict__ Uh, const float* __restrict__ zb,
        float* __restrict__ hplane32, unsigned short* __restrict__ hplane16,
        float* __restrict__ assign_t) {
    extern __shared__ float lds[];
    unsigned short* P = (unsigned short*)lds;
    float* red = lds + 8192;     // [8 wv][8 v][64 lane]
    const int b = blockIdx.x;
    const int k0 = blockIdx.y * 4;
    const int tid = threadIdx.x;
    const int wv = __builtin_amdgcn_readfirstlane(tid >> 6);
    const int lane = tid & 63;
    const int kp = wv >> 2, kiq = wv & 3;

    // prefetch 2 outputs: o = tid + q*512; set = o>>8 in [0,4): kp_o = set>>1, r = set&1
    float preE[2], zvE[2], hpE[2]; bool valE[2]; size_t csE[2], ppE[2];
#pragma unroll
    for (int q = 0; q < 2; ++q) {
        const int o = tid + q * 512;
        const int set = o >> 8, px = o & 255;
        const int kp_o = set >> 1, r = set & 1;
        const int k = k0 + kp_o * 2 + r;
        const int row = px >> 4, col = px & 15;
        valE[q] = (row >= 1 && row <= 14 && col >= 1 && col <= 14);
        csE[q] = ((size_t)b * Kc + k) * Sc + (valE[q] ? (row - 1) * 14 + (col - 1) : 0);
        ppE[q] = (size_t)b * PLB2 + (size_t)k * PX + px;
        preE[q] = 0.f; zvE[q] = 0.f; hpE[q] = 0.f;
        if (valE[q]) {
            preE[q] = wxb_t[csE[q]];
            zvE[q] = zb[csE[q]];
            hpE[q] = hplane32[ppE[q]];
        }
    }
    {
        const float4* src = (const float4*)(rhplane16 + (size_t)b * PLB2);
        float4* dst = (float4*)P;
#pragma unroll
        for (int it = 0; it < 4; ++it) dst[it * 512 + tid] = src[it * 512 + tid];
    }
    __syncthreads();

    const int yp = lane >> 2, xq = (lane & 3) << 2;
    const int rowbase = (yp > 0) ? (yp - 1) : 0;
    const float* uh0 = Uh + (size_t)(k0 + kp * 2) * 576 + kiq * 144;
    float ah[2][4] = {};
    const unsigned short* Pw = P + (size_t)(kiq * 16) * PX + rowbase * 16 + xq;
#pragma unroll 2
    for (int ki = 0; ki < 16; ++ki) {
        const unsigned short* pk = Pw + ki * PX;
#pragma unroll
        for (int dy = 0; dy < 3; ++dy) {
            ushort4 u = *(const ushort4*)(pk + dy * 16);
            float4 m = make_float4(b2f(u.x), b2f(u.y), b2f(u.z), b2f(u.w));
            float e0 = dpp_prev(m.w);
            float e4 = dpp_next(m.x);
#pragma unroll
            for (int r = 0; r < 2; ++r) {
                const float* wh = uh0 + r * 576 + ki * 9 + dy * 3;
                float c0 = wh[0], c1 = wh[1], c2 = wh[2];
                ah[r][0] += c0*e0  + c1*m.x + c2*m.y;
                ah[r][1] += c0*m.x + c1*m.y + c2*m.z;
                ah[r][2] += c0*m.y + c1*m.z + c2*m.w;
                ah[r][3] += c0*m.z + c1*m.w + c2*e4;
            }
        }
    }
    {   // dump red[wv][v][lane], v = r*4+jj
        float* rp = red + (size_t)wv * 512 + lane;
#pragma unroll
        for (int r = 0; r < 2; ++r)
#pragma unroll
            for (int jj = 0; jj < 4; ++jj)
                rp[(size_t)(r * 4 + jj) * 64] = ah[r][jj];
    }
    __syncthreads();
#pragma unroll
    for (int q = 0; q < 2; ++q) {
        const int o = tid + q * 512;
        const int set = o >> 8, px = o & 255;
        const int kp_o = set >> 1, r = set & 1;
        const int lane_r = ((px >> 4) << 2) + ((px & 15) >> 2);
        const int v = r * 4 + (px & 3);
        float s0 = 0.f;
#pragma unroll
        for (int kq2 = 0; kq2 < 4; ++kq2)
            s0 += red[(size_t)((kp_o * 4 + kq2) * 8 + v) * 64 + lane_r];
        if (valE[q]) {
            float hh = tanh_f(preE[q] + s0);
            float hn = (1.f - zvE[q]) * hh + zvE[q] * hpE[q];
            hplane32[ppE[q]] = hn;
            hplane16[ppE[q]] = f2b(hn);
            assign_t[csE[q]] = hn;
        }
    }
}

// ---------------- einsum: grid (4 ch,8 tg,16 b), 256 thr, 68KB LDS ----------------
__global__ __launch_bounds__(256) void k_einsum(const float* __restrict__ x, const float* __restrict__ assign,
                                                float* __restrict__ part) {
    extern __shared__ float lds[];
    float* As = lds;                 // [196][68]
    float* Xs = lds + 196 * 68;      // [28][132]
    const int ch = blockIdx.x, tg = blockIdx.y, b = blockIdx.z;
    const int tid = threadIdx.x;
    const int w = tid >> 6, lane = tid & 63;
    const int kt3 = lane >> 3, ct3 = lane & 7;
    const int kbase = kt3 * 8;
    const int cbase = w * 32 + ct3 * 4;
    float4 acc[8] = {};
    for (int tt = 0; tt < 2; ++tt) {
        const int t = tg * 2 + tt;
        const int n = b * Tc + t;
        __syncthreads();
        {
            const float* ap = assign + ((size_t)t * Bc + b) * KS;
            for (int q = tid; q < 3136; q += 256) {
                int kq = q / Sc, s = q - kq * Sc;
                int k4 = kq * 4;
                float4 v;
                v.x = ap[(size_t)(k4 + 0) * Sc + s];
                v.y = ap[(size_t)(k4 + 1) * Sc + s];
                v.z = ap[(size_t)(k4 + 2) * Sc + s];
                v.w = ap[(size_t)(k4 + 3) * Sc + s];
                *(float4*)(As + (size_t)s * 68 + k4) = v;
            }
        }
        for (int sc = 0; sc < 7; ++sc) {
            const int sb = sc * 28;
            __syncthreads();
            {
                const int c = tid & 127, sh = tid >> 7;
                const float* xp = x + ((size_t)n * Cc + ch * 128 + c) * Sc + sb + sh * 16;
                const int nf = sh ? 3 : 4;
                for (int f = 0; f < nf; ++f) {
                    float4 v = *(const float4*)(xp + f * 4);
                    float* dst = Xs + (size_t)(sh * 16 + f * 4) * 132 + c;
                    dst[0] = v.x; dst[132] = v.y; dst[264] = v.z; dst[396] = v.w;
                }
            }
            __syncthreads();
#pragma unroll 4
            for (int s = 0; s < 28; ++s) {
                const float* ap = As + (size_t)(sb + s) * 68 + kbase;
                float4 a0 = *(const float4*)ap;
                float4 a1 = *(const float4*)(ap + 4);
                float4 xv = *(const float4*)(Xs + (size_t)s * 132 + cbase);
                float av[8] = {a0.x,a0.y,a0.z,a0.w,a1.x,a1.y,a1.z,a1.w};
#pragma unroll
                for (int i = 0; i < 8; ++i) {
                    acc[i].x += av[i] * xv.x;
                    acc[i].y += av[i] * xv.y;
                    acc[i].z += av[i] * xv.z;
                    acc[i].w += av[i] * xv.w;
                }
            }
        }
    }
#pragma unroll
    for (int i = 0; i < 8; ++i) {
        const int k = kbase + i;
        float* op = part + (((size_t)tg * Bc + b) * Kc + k) * Cc + ch * 128 + cbase;
        *(float4*)op = acc[i];
    }
}

// ---------------- reduce: per (b,k): asum + partial-sum + center-subtract + sumsq ----------------
__global__ __launch_bounds__(256) void k_reduce(const float* __restrict__ assign, const float* __restrict__ part,
        const float* __restrict__ centers, float* __restrict__ vlad, float* __restrict__ norm2) {
    __shared__ float redw[4];
    __shared__ float a_s;
    const int blk = blockIdx.x;
    const int b = blk >> 6, k = blk & 63;
    const int tid = threadIdx.x;
    const int wave = tid >> 6, lane = tid & 63;
    const size_t bkoff = ((size_t)b * Kc + k) * Sc;
    float s = 0.f;
    for (int q = tid; q < 784; q += 256) {
        int t = q / 49, s4 = q - t * 49;
        float4 v = *(const float4*)(assign + (size_t)t * BKS + bkoff + s4 * 4);
        s += (v.x + v.y) + (v.z + v.w);
    }
#pragma unroll
    for (int o = 1; o < 64; o <<= 1) s += __shfl_xor(s, o);
    if (lane == 0) redw[wave] = s;
    __syncthreads();
    if (tid == 0) a_s = redw[0] + redw[1] + redw[2] + redw[3];
    __syncthreads();
    const float a = a_s;
    const size_t base = ((size_t)b * Kc + k) * Cc;
    const int c = tid * 2;
    float2 acc2 = make_float2(0.f, 0.f);
#pragma unroll
    for (int g = 0; g < 8; ++g) {
        float2 p = *(const float2*)(part + (size_t)g * GFIN + base + c);
        acc2.x += p.x; acc2.y += p.y;
    }
    float2 cv = *(const float2*)(centers + (size_t)k * Cc + c);
    float v0 = acc2.x - a * cv.x, v1 = acc2.y - a * cv.y;
    *(float2*)(vlad + base + c) = make_float2(v0, v1);
    float ss = v0 * v0 + v1 * v1;
#pragma unroll
    for (int o = 1; o < 64; o <<= 1) ss += __shfl_xor(ss, o);
    __syncthreads();
    if (lane == 0) redw[wave] = ss;
    __syncthreads();
    if (tid == 0) norm2[blk] = redw[0] + redw[1] + redw[2] + redw[3];
}

// ---------------- norms ----------------
__global__ __launch_bounds__(64) void k_norms(const float* __restrict__ norm2, float* __restrict__ scl) {
    const int b = blockIdx.x;
    const int k = threadIdx.x;
    float ss = norm2[b * Kc + k];
    float inv = 1.f / fmaxf(sqrtf(ss), 1e-12f);
    float g = ss * inv * inv;
#pragma unroll
    for (int o = 1; o < 64; o <<= 1) g += __shfl_xor(g, o);
    float gi = 1.f / fmaxf(sqrtf(g), 1e-12f);
    scl[b * Kc + k] = inv * gi;
}

// ---------------- scale ----------------
__global__ __launch_bounds__(256) void k_scale(const float* __restrict__ vlad, const float* __restrict__ scl,
                                               float* __restrict__ out) {
    const int blk = blockIdx.x;           // b*16 + kt
    const int b = blk >> 4, kt = blk & 15;
    const int tid = threadIdx.x;
    const int kk = tid >> 6, lane = tid & 63;
    const int k = kt * 4 + kk;
    const float sv = scl[b * Kc + k];
    const float* vp = vlad + ((size_t)b * Kc + k) * Cc + lane * 8;
    float* op = out + ((size_t)b * Kc + k) * Cc + lane * 8;
    float4 v0 = *(const float4*)vp;
    float4 v1 = *(const float4*)(vp + 4);
    *(float4*)op = make_float4(v0.x * sv, v0.y * sv, v0.z * sv, v0.w * sv);
    *(float4*)(op + 4) = make_float4(v1.x * sv, v1.y * sv, v1.z * sv, v1.w * sv);
}

extern "C" void kernel_launch(void* const* d_in, const int* in_sizes, int n_in,
                              void* d_out, int out_size, void* d_ws, size_t ws_size,
                              hipStream_t stream) {
    (void)in_sizes; (void)n_in; (void)out_size; (void)ws_size;
    const float* x       = (const float*)d_in[0];
    const float* centers = (const float*)d_in[1];
    const float* share_w = (const float*)d_in[2];
    const float* share_b = (const float*)d_in[3];
    const float* Uz      = (const float*)d_in[4];
    const float* Ur      = (const float*)d_in[5];
    const float* Uh      = (const float*)d_in[6];
    float* out = (float*)d_out;
    float* ws  = (float*)d_ws;

    // region A [0, PART_N): wxb [T][B][K][S] + bf16 planes; overlaid by part/vlad after GRU
    float* part      = ws;
    float* vlad      = ws;
    float* wxb       = ws;
    unsigned short* rhplane16 = (unsigned short*)(ws + (size_t)TBKS);            // [B][64][256] bf16
    unsigned short* hplane16  = (unsigned short*)(ws + (size_t)TBKS + 131072);   // [B][64][256] bf16
    float* assign   = ws + (size_t)PART_N;
    float* zb       = assign + (size_t)TBKS;
    float* hplane32 = zb + (size_t)BKS;              // [B][64][256] fp32
    float* wt       = hplane32 + (size_t)Bc * PLB2;
    float* norm2    = wt + (size_t)Kc * Cc;
    float* scl      = norm2 + (size_t)Bc * Kc;

    const size_t gates_lds = 65536;   // 32KB bf16 plane + 32KB red
    const size_t outk_lds  = 49152;   // 32KB plane + 16KB red
    const size_t ein_lds   = (size_t)(196 * 68 + 28 * 132) * 4; // 68.1 KB

    k_transpose_w<<<dim3(128), 256, 0, stream>>>(share_w, wt);
    k_conv1x1<<<dim3(784), 256, 0, stream>>>(x, wt, share_b, wxb);
    k_gru_t0<<<dim3(1024), 64, 0, stream>>>(wxb, hplane32, hplane16, rhplane16, assign);
    for (int t = 1; t < Tc; ++t) {
        k_gru_gates<<<dim3(16, 16), 512, gates_lds, stream>>>(hplane16, wxb + (size_t)t * BKS,
                                                              Uz, Ur, zb, rhplane16);
        k_gru_out<<<dim3(16, 16), 512, outk_lds, stream>>>(rhplane16, wxb + (size_t)t * BKS,
                                                           Uh, zb, hplane32, hplane16,
                                                           assign + (size_t)t * BKS);
    }
    k_einsum<<<dim3(4, 8, 16), 256, ein_lds, stream>>>(x, assign, part);
    k_reduce<<<dim3(Bc * Kc), 256, 0, stream>>>(assign, part, centers, vlad, norm2);
    k_norms<<<dim3(Bc), 64, 0, stream>>>(norm2, scl);
    k_scale<<<dim3(256), 256, 0, stream>>>(vlad, scl, out);
}

// Round 12
// 455.021 us; speedup vs baseline: 1.6865x; 1.0094x over previous
//
#include <hip/hip_runtime.h>

#define Bc 16
#define Tc 16
#define Cc 512
#define Kc 64
#define Sc 196
#define KS (Kc*Sc)          // 12544
#define BKS (Bc*Kc*Sc)      // 200704
#define TBKS (Tc*BKS)       // 3211264
#define GFIN (16*64*512)    // 524288
#define PART_N (8*GFIN)     // 4194304
#define PX 256              // 16 rows * 16 cols per plane
#define PLB2 (Kc*PX)        // 16384 elems per b

typedef __attribute__((ext_vector_type(8))) short bf16x8;
typedef __attribute__((ext_vector_type(4))) float f32x4;

__device__ __forceinline__ float sigmoid_f(float x) { return 1.f / (1.f + __expf(-x)); }
__device__ __forceinline__ float tanh_f(float x) { return 1.f - 2.f / (__expf(2.f * x) + 1.f); }

__device__ __forceinline__ float b2f(unsigned short u) {
    return __uint_as_float(((unsigned)u) << 16);
}
__device__ __forceinline__ unsigned short f2b(float f) {   // RNE
    unsigned u = __float_as_uint(f);
    return (unsigned short)((u + 0x7FFFu + ((u >> 16) & 1u)) >> 16);
}
// split f = hi + lo (hi = truncated-mantissa bf16, exactly representable; lo = residual)
__device__ __forceinline__ void split1(float f, unsigned short& h, unsigned short& l) {
    unsigned u = __float_as_uint(f);
    unsigned uh = u & 0xffff0000u;
    h = (unsigned short)(uh >> 16);
    float fl = f - __uint_as_float(uh);
    l = (unsigned short)(__float_as_uint(fl) >> 16);
}

// neighbor-lane reads within 16-lane DPP rows; out-of-range -> 0 (bound_ctrl)
__device__ __forceinline__ float dpp_prev(float v) {
    return __int_as_float(__builtin_amdgcn_mov_dpp(__float_as_int(v), 0x111, 0xf, 0xf, true));
}
__device__ __forceinline__ float dpp_next(float v) {
    return __int_as_float(__builtin_amdgcn_mov_dpp(__float_as_int(v), 0x101, 0xf, 0xf, true));
}

// ---------------- prep W: split share_w [64][512] into bf16 hi/lo ----------------
__global__ __launch_bounds__(256) void k_prep_w(const float* __restrict__ w,
        unsigned short* __restrict__ wh, unsigned short* __restrict__ wl) {
    int idx = blockIdx.x * 256 + threadIdx.x;   // 32768 total
    unsigned short h, l;
    split1(w[idx], h, l);
    wh[idx] = h; wl[idx] = l;
}

// ---------------- conv1x1 via MFMA: D[gs][k] = X^T[gs][c] * W^T[c][k], bf16x3 split ----------------
// grid 784 (64 gs each), 512 thr = 8 waves: wave = (mt = w&3 gs-tile) x (np = w>>2 k-pair)
__global__ __launch_bounds__(512) void k_conv1x1(const float* __restrict__ x,
        const unsigned short* __restrict__ wh, const unsigned short* __restrict__ wl,
        const float* __restrict__ bias, float* __restrict__ wxb) {
    extern __shared__ float lds[];
    unsigned short* Xh = (unsigned short*)lds;   // [64 gs][40 c-pad]
    unsigned short* Xl = Xh + 64 * 40;
    const int gs0 = blockIdx.x * 64;
    const int tid = threadIdx.x;
    const int wv = tid >> 6, lane = tid & 63;
    const int lg = lane >> 4, ln = lane & 15;
    const int mt = wv & 3, np = wv >> 2;
    // staging: thread owns one gs column, 4 c per chunk
    const int colS = tid & 63, cgS = tid >> 6;
    const int gsS = gs0 + colS;
    const int nS = gsS / Sc, sS = gsS - nS * Sc;
    const float* xcol = x + (size_t)nS * (Cc * Sc) + sS;
    const int kA = np * 32 + ln;           // acc0 k ; acc1 k = kA+16
    const float bias0 = bias[kA], bias1 = bias[kA + 16];

    f32x4 acc0 = {0.f, 0.f, 0.f, 0.f}, acc1 = {0.f, 0.f, 0.f, 0.f};
    for (int c0 = 0; c0 < Cc; c0 += 32) {
        __syncthreads();
#pragma unroll
        for (int q = 0; q < 4; ++q) {
            const int cl = cgS * 4 + q;
            unsigned short h, l;
            split1(xcol[(size_t)(c0 + cl) * Sc], h, l);
            Xh[colS * 40 + cl] = h;
            Xl[colS * 40 + cl] = l;
        }
        __syncthreads();
        bf16x8 B0h = *(const bf16x8*)(wh + (size_t)kA * Cc + c0 + lg * 8);
        bf16x8 B0l = *(const bf16x8*)(wl + (size_t)kA * Cc + c0 + lg * 8);
        bf16x8 B1h = *(const bf16x8*)(wh + (size_t)(kA + 16) * Cc + c0 + lg * 8);
        bf16x8 B1l = *(const bf16x8*)(wl + (size_t)(kA + 16) * Cc + c0 + lg * 8);
        bf16x8 Af = *(const bf16x8*)(Xh + (mt * 16 + ln) * 40 + lg * 8);
        bf16x8 Al = *(const bf16x8*)(Xl + (mt * 16 + ln) * 40 + lg * 8);
        acc0 = __builtin_amdgcn_mfma_f32_16x16x32_bf16(Af, B0h, acc0, 0, 0, 0);
        acc0 = __builtin_amdgcn_mfma_f32_16x16x32_bf16(Al, B0h, acc0, 0, 0, 0);
        acc0 = __builtin_amdgcn_mfma_f32_16x16x32_bf16(Af, B0l, acc0, 0, 0, 0);
        acc1 = __builtin_amdgcn_mfma_f32_16x16x32_bf16(Af, B1h, acc1, 0, 0, 0);
        acc1 = __builtin_amdgcn_mfma_f32_16x16x32_bf16(Al, B1h, acc1, 0, 0, 0);
        acc1 = __builtin_amdgcn_mfma_f32_16x16x32_bf16(Af, B1l, acc1, 0, 0, 0);
    }
#pragma unroll
    for (int r = 0; r < 4; ++r) {
        const int gs = gs0 + mt * 16 + lg * 4 + r;
        const int n = gs / Sc, s = gs - (gs / Sc) * Sc;
        const int t = n & 15, bb = n >> 4;
        const size_t rowbase = ((size_t)t * Bc + bb) * Kc;
        wxb[(rowbase + kA) * Sc + s] = acc0[r] + bias0;
        wxb[(rowbase + kA + 16) * Sc + s] = acc1[r] + bias1;
    }
}

// ---------------- GRU t=0: h0=0 -> h = (1-sig(wxb))*tanh(wxb); init planes ----------------
__global__ __launch_bounds__(64) void k_gru_t0(const float* __restrict__ wxb,
        float* __restrict__ hplane32, unsigned short* __restrict__ hplane16,
        unsigned short* __restrict__ rhplane16, float* __restrict__ assign) {
    const int blk = blockIdx.x;             // b*64 + k
    const size_t pbase = (size_t)blk * PX;
    const size_t cbase = (size_t)blk * Sc;
    for (int i = threadIdx.x; i < PX; i += 64) {
        int row = i >> 4, col = i & 15;
        float v = 0.f;
        if (row >= 1 && row <= 14 && col >= 1 && col <= 14) {
            int s = (row - 1) * 14 + (col - 1);
            float pre = wxb[cbase + s];
            v = (1.f - sigmoid_f(pre)) * tanh_f(pre);
            assign[cbase + s] = v;
        }
        hplane32[pbase + i] = v;
        hplane16[pbase + i] = f2b(v);
        rhplane16[pbase + i] = 0;
    }
}

// ---------------- GRU gates: grid (16 b, 16 kt), 512 thr = 8 waves = (kp 2) x (kiq 4) ----------------
__global__ __launch_bounds__(512) void k_gru_gates(const unsigned short* __restrict__ hplane16,
        const float* __restrict__ wxb_t, const float* __restrict__ Uz, const float* __restrict__ Ur,
        float* __restrict__ zb, unsigned short* __restrict__ rhplane16) {
    extern __shared__ float lds[];
    unsigned short* P = (unsigned short*)lds;   // [64][256] bf16
    float* red = lds + 8192;
    const int b = blockIdx.x;
    const int k0 = blockIdx.y * 4;
    const int tid = threadIdx.x;
    const int wv = __builtin_amdgcn_readfirstlane(tid >> 6);
    const int lane = tid & 63;
    const int kp = wv >> 2, kiq = wv & 3;

    float preE[4]; bool valE[4]; size_t csE[4]; int kEa[4];
#pragma unroll
    for (int q = 0; q < 4; ++q) {
        const int o = tid + q * 512;
        const int set = o >> 8, px = o & 255;
        const int kp_o = set >> 2, r = set & 1;
        kEa[q] = k0 + kp_o * 2 + r;
        const int row = px >> 4, col = px & 15;
        valE[q] = (row >= 1 && row <= 14 && col >= 1 && col <= 14);
        csE[q] = ((size_t)b * Kc + kEa[q]) * Sc + (valE[q] ? (row - 1) * 14 + (col - 1) : 0);
        preE[q] = valE[q] ? wxb_t[csE[q]] : 0.f;
    }
    {
        const float4* src = (const float4*)(hplane16 + (size_t)b * PLB2);
        float4* dst = (float4*)P;
#pragma unroll
        for (int it = 0; it < 4; ++it) dst[it * 512 + tid] = src[it * 512 + tid];
    }
    __syncthreads();

    const int yp = lane >> 2, xq = (lane & 3) << 2;
    const int rowbase = (yp > 0) ? (yp - 1) : 0;
    const float* uz0 = Uz + (size_t)(k0 + kp * 2) * 576 + kiq * 144;
    const float* ur0 = Ur + (size_t)(k0 + kp * 2) * 576 + kiq * 144;
    float az[2][4] = {}, ar[2][4] = {};
    const unsigned short* Pw = P + (size_t)(kiq * 16) * PX + rowbase * 16 + xq;
#pragma unroll 2
    for (int ki = 0; ki < 16; ++ki) {
        const unsigned short* pk = Pw + ki * PX;
#pragma unroll
        for (int dy = 0; dy < 3; ++dy) {
            ushort4 u = *(const ushort4*)(pk + dy * 16);
            float4 m = make_float4(b2f(u.x), b2f(u.y), b2f(u.z), b2f(u.w));
            float e0 = dpp_prev(m.w);
            float e4 = dpp_next(m.x);
#pragma unroll
            for (int r = 0; r < 2; ++r) {
                const float* wz = uz0 + r * 576 + ki * 9 + dy * 3;
                float c0 = wz[0], c1 = wz[1], c2 = wz[2];
                az[r][0] += c0*e0  + c1*m.x + c2*m.y;
                az[r][1] += c0*m.x + c1*m.y + c2*m.z;
                az[r][2] += c0*m.y + c1*m.z + c2*m.w;
                az[r][3] += c0*m.z + c1*m.w + c2*e4;
                const float* wr = ur0 + r * 576 + ki * 9 + dy * 3;
                float d0 = wr[0], d1 = wr[1], d2 = wr[2];
                ar[r][0] += d0*e0  + d1*m.x + d2*m.y;
                ar[r][1] += d0*m.x + d1*m.y + d2*m.z;
                ar[r][2] += d0*m.y + d1*m.z + d2*m.w;
                ar[r][3] += d0*m.z + d1*m.w + d2*e4;
            }
        }
    }
    {
        float* rp = red + (size_t)wv * 1024 + lane;
#pragma unroll
        for (int r = 0; r < 2; ++r)
#pragma unroll
            for (int jj = 0; jj < 4; ++jj) {
                rp[(size_t)(r * 4 + jj) * 64] = az[r][jj];
                rp[(size_t)(8 + r * 4 + jj) * 64] = ar[r][jj];
            }
    }
    __syncthreads();
#pragma unroll
    for (int q = 0; q < 4; ++q) {
        const int o = tid + q * 512;
        const int set = o >> 8, px = o & 255;
        const int kp_o = set >> 2, g = (set >> 1) & 1, r = set & 1;
        const int lane_r = ((px >> 4) << 2) + ((px & 15) >> 2);
        const int v = (g * 2 + r) * 4 + (px & 3);
        float s0 = 0.f;
#pragma unroll
        for (int kq2 = 0; kq2 < 4; ++kq2)
            s0 += red[(size_t)((kp_o * 4 + kq2) * 16 + v) * 64 + lane_r];
        if (valE[q]) {
            float sv = sigmoid_f(preE[q] + s0);
            if (g == 0) {
                zb[csE[q]] = sv;
            } else {
                float hv = b2f(P[(size_t)kEa[q] * PX + px]);
                rhplane16[(size_t)b * PLB2 + (size_t)kEa[q] * PX + px] = f2b(sv * hv);
            }
        }
    }
}

// ---------------- GRU out ----------------
__global__ __launch_bounds__(512) void k_gru_out(const unsigned short* __restrict__ rhplane16,
        const float* __restrict__ wxb_t, const float* __restrict__ Uh, const float* __restrict__ zb,
        float* __restrict__ hplane32, unsigned short* __restrict__ hplane16,
        float* __restrict__ assign_t) {
    extern __shared__ float lds[];
    unsigned short* P = (unsigned short*)lds;
    float* red = lds + 8192;
    const int b = blockIdx.x;
    const int k0 = blockIdx.y * 4;
    const int tid = threadIdx.x;
    const int wv = __builtin_amdgcn_readfirstlane(tid >> 6);
    const int lane = tid & 63;
    const int kp = wv >> 2, kiq = wv & 3;

    float preE[2], zvE[2], hpE[2]; bool valE[2]; size_t csE[2], ppE[2];
#pragma unroll
    for (int q = 0; q < 2; ++q) {
        const int o = tid + q * 512;
        const int set = o >> 8, px = o & 255;
        const int kp_o = set >> 1, r = set & 1;
        const int k = k0 + kp_o * 2 + r;
        const int row = px >> 4, col = px & 15;
        valE[q] = (row >= 1 && row <= 14 && col >= 1 && col <= 14);
        csE[q] = ((size_t)b * Kc + k) * Sc + (valE[q] ? (row - 1) * 14 + (col - 1) : 0);
        ppE[q] = (size_t)b * PLB2 + (size_t)k * PX + px;
        preE[q] = 0.f; zvE[q] = 0.f; hpE[q] = 0.f;
        if (valE[q]) {
            preE[q] = wxb_t[csE[q]];
            zvE[q] = zb[csE[q]];
            hpE[q] = hplane32[ppE[q]];
        }
    }
    {
        const float4* src = (const float4*)(rhplane16 + (size_t)b * PLB2);
        float4* dst = (float4*)P;
#pragma unroll
        for (int it = 0; it < 4; ++it) dst[it * 512 + tid] = src[it * 512 + tid];
    }
    __syncthreads();

    const int yp = lane >> 2, xq = (lane & 3) << 2;
    const int rowbase = (yp > 0) ? (yp - 1) : 0;
    const float* uh0 = Uh + (size_t)(k0 + kp * 2) * 576 + kiq * 144;
    float ah[2][4] = {};
    const unsigned short* Pw = P + (size_t)(kiq * 16) * PX + rowbase * 16 + xq;
#pragma unroll 2
    for (int ki = 0; ki < 16; ++ki) {
        const unsigned short* pk = Pw + ki * PX;
#pragma unroll
        for (int dy = 0; dy < 3; ++dy) {
            ushort4 u = *(const ushort4*)(pk + dy * 16);
            float4 m = make_float4(b2f(u.x), b2f(u.y), b2f(u.z), b2f(u.w));
            float e0 = dpp_prev(m.w);
            float e4 = dpp_next(m.x);
#pragma unroll
            for (int r = 0; r < 2; ++r) {
                const float* wh = uh0 + r * 576 + ki * 9 + dy * 3;
                float c0 = wh[0], c1 = wh[1], c2 = wh[2];
                ah[r][0] += c0*e0  + c1*m.x + c2*m.y;
                ah[r][1] += c0*m.x + c1*m.y + c2*m.z;
                ah[r][2] += c0*m.y + c1*m.z + c2*m.w;
                ah[r][3] += c0*m.z + c1*m.w + c2*e4;
            }
        }
    }
    {
        float* rp = red + (size_t)wv * 512 + lane;
#pragma unroll
        for (int r = 0; r < 2; ++r)
#pragma unroll
            for (int jj = 0; jj < 4; ++jj)
                rp[(size_t)(r * 4 + jj) * 64] = ah[r][jj];
    }
    __syncthreads();
#pragma unroll
    for (int q = 0; q < 2; ++q) {
        const int o = tid + q * 512;
        const int set = o >> 8, px = o & 255;
        const int kp_o = set >> 1, r = set & 1;
        const int lane_r = ((px >> 4) << 2) + ((px & 15) >> 2);
        const int v = r * 4 + (px & 3);
        float s0 = 0.f;
#pragma unroll
        for (int kq2 = 0; kq2 < 4; ++kq2)
            s0 += red[(size_t)((kp_o * 4 + kq2) * 8 + v) * 64 + lane_r];
        if (valE[q]) {
            float hh = tanh_f(preE[q] + s0);
            float hn = (1.f - zvE[q]) * hh + zvE[q] * hpE[q];
            hplane32[ppE[q]] = hn;
            hplane16[ppE[q]] = f2b(hn);
            assign_t[csE[q]] = hn;
        }
    }
}

// ---------------- einsum via MFMA: part[tg][b][k][c] = sum_{t in tg,s} assign[k][s] * x[c][s] ----------------
// grid (4 cq, 8 tg, 16 b), 512 thr = 8 waves; wave = N-tile (16 c), 4 M-tiles (k) each
__global__ __launch_bounds__(512) void k_einsum(const float* __restrict__ x, const float* __restrict__ assign,
                                                float* __restrict__ part) {
    extern __shared__ float lds[];
    unsigned short* Ah = (unsigned short*)lds;      // [64 k][40 s-pad]
    unsigned short* Al = Ah + 64 * 40;
    unsigned short* Xh = Al + 64 * 40;              // [128 c][40 s-pad]
    unsigned short* Xl = Xh + 128 * 40;
    const int cq = blockIdx.x, tg = blockIdx.y, b = blockIdx.z;
    const int tid = threadIdx.x;
    const int wv = tid >> 6, lane = tid & 63;
    const int lg = lane >> 4, ln = lane & 15;
    const int ka = tid >> 3, ss4 = (tid & 7) * 4;   // A staging: k row, s offset
    const int cx = tid >> 2, ss8 = (tid & 3) * 8;   // X staging: c row, s offset

    f32x4 acc[4];
#pragma unroll
    for (int mt = 0; mt < 4; ++mt) acc[mt] = (f32x4){0.f, 0.f, 0.f, 0.f};

    for (int tt = 0; tt < 2; ++tt) {
        const int t = tg * 2 + tt;
        const int n = b * Tc + t;
        const float* ap = assign + ((size_t)t * Bc + b) * KS;
        const float* xp = x + ((size_t)n * Cc + cq * 128) * Sc;
        for (int sc7 = 0; sc7 < 7; ++sc7) {
            const int s0 = sc7 * 32;
            __syncthreads();
            {   // A tile [64][32]
                float4 v = make_float4(0.f, 0.f, 0.f, 0.f);
                if (s0 + ss4 <= 192) v = *(const float4*)(ap + (size_t)ka * Sc + s0 + ss4);
                ushort4 h, l;
                split1(v.x, h.x, l.x); split1(v.y, h.y, l.y);
                split1(v.z, h.z, l.z); split1(v.w, h.w, l.w);
                *(ushort4*)(Ah + ka * 40 + ss4) = h;
                *(ushort4*)(Al + ka * 40 + ss4) = l;
            }
#pragma unroll
            for (int q = 0; q < 2; ++q) {   // X tile [128][32]
                const int so = ss8 + q * 4;
                float4 v = make_float4(0.f, 0.f, 0.f, 0.f);
                if (s0 + so <= 192) v = *(const float4*)(xp + (size_t)cx * Sc + s0 + so);
                ushort4 h, l;
                split1(v.x, h.x, l.x); split1(v.y, h.y, l.y);
                split1(v.z, h.z, l.z); split1(v.w, h.w, l.w);
                *(ushort4*)(Xh + cx * 40 + so) = h;
                *(ushort4*)(Xl + cx * 40 + so) = l;
            }
            __syncthreads();
            bf16x8 Bh = *(const bf16x8*)(Xh + (wv * 16 + ln) * 40 + lg * 8);
            bf16x8 Bl = *(const bf16x8*)(Xl + (wv * 16 + ln) * 40 + lg * 8);
#pragma unroll
            for (int mt = 0; mt < 4; ++mt) {
                bf16x8 Af = *(const bf16x8*)(Ah + (mt * 16 + ln) * 40 + lg * 8);
                bf16x8 Alo = *(const bf16x8*)(Al + (mt * 16 + ln) * 40 + lg * 8);
                acc[mt] = __builtin_amdgcn_mfma_f32_16x16x32_bf16(Af, Bh, acc[mt], 0, 0, 0);
                acc[mt] = __builtin_amdgcn_mfma_f32_16x16x32_bf16(Alo, Bh, acc[mt], 0, 0, 0);
                acc[mt] = __builtin_amdgcn_mfma_f32_16x16x32_bf16(Af, Bl, acc[mt], 0, 0, 0);
            }
        }
    }
    const int c = cq * 128 + wv * 16 + ln;
#pragma unroll
    for (int mt = 0; mt < 4; ++mt) {
#pragma unroll
        for (int r = 0; r < 4; ++r) {
            const int k = mt * 16 + lg * 4 + r;
            part[(((size_t)tg * Bc + b) * Kc + k) * Cc + c] = acc[mt][r];
        }
    }
}

// ---------------- reduce: per (b,k): asum + partial-sum + center-subtract + sumsq ----------------
__global__ __launch_bounds__(256) void k_reduce(const float* __restrict__ assign, const float* __restrict__ part,
        const float* __restrict__ centers, float* __restrict__ vlad, float* __restrict__ norm2) {
    __shared__ float redw[4];
    __shared__ float a_s;
    const int blk = blockIdx.x;
    const int b = blk >> 6, k = blk & 63;
    const int tid = threadIdx.x;
    const int wave = tid >> 6, lane = tid & 63;
    const size_t bkoff = ((size_t)b * Kc + k) * Sc;
    float s = 0.f;
    for (int q = tid; q < 784; q += 256) {
        int t = q / 49, s4 = q - t * 49;
        float4 v = *(const float4*)(assign + (size_t)t * BKS + bkoff + s4 * 4);
        s += (v.x + v.y) + (v.z + v.w);
    }
#pragma unroll
    for (int o = 1; o < 64; o <<= 1) s += __shfl_xor(s, o);
    if (lane == 0) redw[wave] = s;
    __syncthreads();
    if (tid == 0) a_s = redw[0] + redw[1] + redw[2] + redw[3];
    __syncthreads();
    const float a = a_s;
    const size_t base = ((size_t)b * Kc + k) * Cc;
    const int c = tid * 2;
    float2 acc2 = make_float2(0.f, 0.f);
#pragma unroll
    for (int g = 0; g < 8; ++g) {
        float2 p = *(const float2*)(part + (size_t)g * GFIN + base + c);
        acc2.x += p.x; acc2.y += p.y;
    }
    float2 cv = *(const float2*)(centers + (size_t)k * Cc + c);
    float v0 = acc2.x - a * cv.x, v1 = acc2.y - a * cv.y;
    *(float2*)(vlad + base + c) = make_float2(v0, v1);
    float ss = v0 * v0 + v1 * v1;
#pragma unroll
    for (int o = 1; o < 64; o <<= 1) ss += __shfl_xor(ss, o);
    __syncthreads();
    if (lane == 0) redw[wave] = ss;
    __syncthreads();
    if (tid == 0) norm2[blk] = redw[0] + redw[1] + redw[2] + redw[3];
}

// ---------------- norms ----------------
__global__ __launch_bounds__(64) void k_norms(const float* __restrict__ norm2, float* __restrict__ scl) {
    const int b = blockIdx.x;
    const int k = threadIdx.x;
    float ss = norm2[b * Kc + k];
    float inv = 1.f / fmaxf(sqrtf(ss), 1e-12f);
    float g = ss * inv * inv;
#pragma unroll
    for (int o = 1; o < 64; o <<= 1) g += __shfl_xor(g, o);
    float gi = 1.f / fmaxf(sqrtf(g), 1e-12f);
    scl[b * Kc + k] = inv * gi;
}

// ---------------- scale ----------------
__global__ __launch_bounds__(256) void k_scale(const float* __restrict__ vlad, const float* __restrict__ scl,
                                               float* __restrict__ out) {
    const int blk = blockIdx.x;           // b*16 + kt
    const int b = blk >> 4, kt = blk & 15;
    const int tid = threadIdx.x;
    const int kk = tid >> 6, lane = tid & 63;
    const int k = kt * 4 + kk;
    const float sv = scl[b * Kc + k];
    const float* vp = vlad + ((size_t)b * Kc + k) * Cc + lane * 8;
    float* op = out + ((size_t)b * Kc + k) * Cc + lane * 8;
    float4 v0 = *(const float4*)vp;
    float4 v1 = *(const float4*)(vp + 4);
    *(float4*)op = make_float4(v0.x * sv, v0.y * sv, v0.z * sv, v0.w * sv);
    *(float4*)(op + 4) = make_float4(v1.x * sv, v1.y * sv, v1.z * sv, v1.w * sv);
}

extern "C" void kernel_launch(void* const* d_in, const int* in_sizes, int n_in,
                              void* d_out, int out_size, void* d_ws, size_t ws_size,
                              hipStream_t stream) {
    (void)in_sizes; (void)n_in; (void)out_size; (void)ws_size;
    const float* x       = (const float*)d_in[0];
    const float* centers = (const float*)d_in[1];
    const float* share_w = (const float*)d_in[2];
    const float* share_b = (const float*)d_in[3];
    const float* Uz      = (const float*)d_in[4];
    const float* Ur      = (const float*)d_in[5];
    const float* Uh      = (const float*)d_in[6];
    float* out = (float*)d_out;
    float* ws  = (float*)d_ws;

    float* part      = ws;
    float* vlad      = ws;
    float* wxb       = ws;
    unsigned short* rhplane16 = (unsigned short*)(ws + (size_t)TBKS);            // [B][64][256] bf16
    unsigned short* hplane16  = (unsigned short*)(ws + (size_t)TBKS + 131072);   // [B][64][256] bf16
    float* assign   = ws + (size_t)PART_N;
    float* zb       = assign + (size_t)TBKS;
    float* hplane32 = zb + (size_t)BKS;              // [B][64][256] fp32
    float* wreg     = hplane32 + (size_t)Bc * PLB2;  // Kc*Cc floats region reused for w_hi/w_lo
    unsigned short* w_hi = (unsigned short*)wreg;
    unsigned short* w_lo = w_hi + (size_t)Kc * Cc;
    float* norm2    = wreg + (size_t)Kc * Cc;
    float* scl      = norm2 + (size_t)Bc * Kc;

    const size_t conv_lds  = 64 * 40 * 2 * 2;                    // 10.2 KB
    const size_t gates_lds = 65536;                              // 32KB plane + 32KB red
    const size_t outk_lds  = 49152;                              // 32KB plane + 16KB red
    const size_t ein_lds   = (64 * 40 + 128 * 40) * 2 * 2;       // 30.7 KB

    k_prep_w<<<dim3(128), 256, 0, stream>>>(share_w, w_hi, w_lo);
    k_conv1x1<<<dim3(784), 512, conv_lds, stream>>>(x, w_hi, w_lo, share_b, wxb);
    k_gru_t0<<<dim3(1024), 64, 0, stream>>>(wxb, hplane32, hplane16, rhplane16, assign);
    for (int t = 1; t < Tc; ++t) {
        k_gru_gates<<<dim3(16, 16), 512, gates_lds, stream>>>(hplane16, wxb + (size_t)t * BKS,
                                                              Uz, Ur, zb, rhplane16);
        k_gru_out<<<dim3(16, 16), 512, outk_lds, stream>>>(rhplane16, wxb + (size_t)t * BKS,
                                                           Uh, zb, hplane32, hplane16,
                                                           assign + (size_t)t * BKS);
    }
    k_einsum<<<dim3(4, 8, 16), 512, ein_lds, stream>>>(x, assign, part);
    k_reduce<<<dim3(Bc * Kc), 256, 0, stream>>>(assign, part, centers, vlad, norm2);
    k_norms<<<dim3(Bc), 64, 0, stream>>>(norm2, scl);
    k_scale<<<dim3(256), 256, 0, stream>>>(vlad, scl, out);
}